// Round 2
// baseline (3691.312 us; speedup 1.0000x reference)
//
#include <hip/hip_runtime.h>
#include <hip/hip_bf16.h>
#include <stdint.h>

#define DEPTH 4
#define DIM   1024
#define DH    4096
#define NH    8
#define DQ    128
#define VOC   32000
#define BATCH 2
#define SEQ   1024
#define ROWS  (BATCH*SEQ)   // 2048

#define PQKV ((long long)ROWS*DIM)
#define PROT ((long long)BATCH*NH*SEQ*2*DQ)
#define PVT  ((long long)BATCH*NH*DQ*SEQ)
#define PS   ((long long)BATCH*NH*SEQ*SEQ)
#define PMID ((long long)ROWS*DH)
#define PY   ((long long)ROWS*DIM)
#define PLC  ((long long)NH*DQ*2*DQ)

typedef __hip_bfloat16 bf16;
using f32x4  = __attribute__((ext_vector_type(4))) float;
using bf16x8 = __attribute__((ext_vector_type(8))) __bf16;

__device__ __forceinline__ void wpair(bf16* p, long long off, long long plane, float v) {
  bf16 hi = __float2bfloat16(v);
  p[off] = hi;
  p[off + plane] = __float2bfloat16(v - __bfloat162float(hi));
}

__device__ __forceinline__ void gload_lds16(const void* g, void* l) {
  __builtin_amdgcn_global_load_lds(
      (const __attribute__((address_space(1))) void*)g,
      (__attribute__((address_space(3))) void*)(uintptr_t)l,
      16, 0, 0);
}

// ---------------------------------------------------------------------------
// Batched GEMM: C[z] = A[z] (MxK rm) * B[z%bmod]^T (NxK rm)
// SA/SB: operand is a bf16 hi/lo pair (lo plane at +pA/+pB elements);
// 3-pass compensated product Ah*Bh + Al*Bh + Ah*Bl (~fp32 input precision).
// EPI 0: f32 C = acc+bias          3: f32 C += acc+bias
//     5: pair C = acc+bias         6: pair C = silu(acc+bias)
//     7: pair C = acc*decay, decay = a^(row-col) for row>=col else 0,
//        a = sigmoid(bias[z%hmod])
// ---------------------------------------------------------------------------
#define BM 128
#define BN 128
#define BKK 64
#define PL 16384   // one LDS plane: 128 rows x 64 bf16

template<int EPI, int SA, int SB>
__global__ __launch_bounds__(256, (SA || SB) ? 2 : 4)
void gemm_bt(const bf16* __restrict__ A, long long sA, long long pA, int lda,
             const bf16* __restrict__ B, long long sB, long long pB, int ldb, int bmod,
             void* __restrict__ Cv, long long sC, long long pC, int ldc,
             const float* __restrict__ bias, int hmod,
             int M, int N, int K)
{
  __shared__ int4 sbuf[1024 * (2 + SA + SB)];
  char* Asb = (char*)sbuf;
  char* Bsb = Asb + PL * (1 + SA);

  const int tid  = threadIdx.x;
  const int lane = tid & 63;
  const int wave = tid >> 6;
  const int wr   = wave >> 1;
  const int wc   = wave & 1;
  const int z    = blockIdx.z;
  const long long tm = (long long)blockIdx.y * BM;
  const long long tn = (long long)blockIdx.x * BN;

  const bf16* Ab = A + (long long)z * sA;
  const bf16* Bb = B + (long long)(z % bmod) * sB;

  f32x4 acc[4][4] = {};

  for (int kt = 0; kt < K; kt += BKK) {
#pragma unroll
    for (int j = 0; j < 4; ++j) {
      int slot0 = j*256 + wave*64;          // wave-uniform LDS base
      int i = slot0 + lane;
      int row = i >> 3;
      int gc  = (i & 7) ^ (row & 7);        // inverse-swizzled global chunk
      long long ga = (tm + row) * (long long)lda + kt + gc*8;
      long long gb = (tn + row) * (long long)ldb + kt + gc*8;
      gload_lds16(Ab + ga, Asb + slot0*16);
      if (SA) gload_lds16(Ab + pA + ga, Asb + PL + slot0*16);
      gload_lds16(Bb + gb, Bsb + slot0*16);
      if (SB) gload_lds16(Bb + pB + gb, Bsb + PL + slot0*16);
    }
    __syncthreads();
#pragma unroll
    for (int kh = 0; kh < 2; ++kh) {
      const int cb = kh*4 + (lane >> 4);
      int4 avh[4], bvh[4], avl[4], bvl[4];
#pragma unroll
      for (int mi = 0; mi < 4; ++mi) {
        int m = wr*64 + mi*16 + (lane & 15);
        int off = m*128 + ((cb ^ (m & 7)) << 4);
        avh[mi] = *(const int4*)(Asb + off);
        if (SA) avl[mi] = *(const int4*)(Asb + PL + off);
      }
#pragma unroll
      for (int nj = 0; nj < 4; ++nj) {
        int n = wc*64 + nj*16 + (lane & 15);
        int off = n*128 + ((cb ^ (n & 7)) << 4);
        bvh[nj] = *(const int4*)(Bsb + off);
        if (SB) bvl[nj] = *(const int4*)(Bsb + PL + off);
      }
#pragma unroll
      for (int mi = 0; mi < 4; ++mi)
#pragma unroll
        for (int nj = 0; nj < 4; ++nj)
          acc[mi][nj] = __builtin_amdgcn_mfma_f32_16x16x32_bf16(
              __builtin_bit_cast(bf16x8, avh[mi]),
              __builtin_bit_cast(bf16x8, bvh[nj]), acc[mi][nj], 0, 0, 0);
      if (SA)
#pragma unroll
        for (int mi = 0; mi < 4; ++mi)
#pragma unroll
          for (int nj = 0; nj < 4; ++nj)
            acc[mi][nj] = __builtin_amdgcn_mfma_f32_16x16x32_bf16(
                __builtin_bit_cast(bf16x8, avl[mi]),
                __builtin_bit_cast(bf16x8, bvh[nj]), acc[mi][nj], 0, 0, 0);
      if (SB)
#pragma unroll
        for (int mi = 0; mi < 4; ++mi)
#pragma unroll
          for (int nj = 0; nj < 4; ++nj)
            acc[mi][nj] = __builtin_amdgcn_mfma_f32_16x16x32_bf16(
                __builtin_bit_cast(bf16x8, avh[mi]),
                __builtin_bit_cast(bf16x8, bvl[nj]), acc[mi][nj], 0, 0, 0);
    }
    __syncthreads();
  }

  float aa = 0.f;
  if (EPI == 7) aa = 1.f / (1.f + __expf(-bias[z % hmod]));
  const int col = lane & 15;
  const int rb  = (lane >> 4) << 2;
  float* Cf = (float*)Cv + (long long)z * sC;
  bf16*  Ch = (bf16*) Cv + (long long)z * sC;

#pragma unroll
  for (int mi = 0; mi < 4; ++mi)
#pragma unroll
    for (int nj = 0; nj < 4; ++nj) {
      long long gn = tn + wc*64 + nj*16 + col;
      float bv_ = (EPI != 7 && bias) ? bias[gn] : 0.f;
#pragma unroll
      for (int r = 0; r < 4; ++r) {
        long long gm = tm + wr*64 + mi*16 + rb + r;
        float v = acc[mi][nj][r] + bv_;
        long long off = gm * (long long)ldc + gn;
        if (EPI == 0)      Cf[off] = v;
        else if (EPI == 3) Cf[off] += v;
        else if (EPI == 5) wpair(Ch, off, pC, v);
        else if (EPI == 6) wpair(Ch, off, pC, v / (1.f + __expf(-v)));
        else {
          long long dlt = gm - gn;
          float dcy = (dlt >= 0) ? powf(aa, (float)dlt) : 0.f;
          wpair(Ch, off, pC, acc[mi][nj][r] * dcy);
        }
      }
    }
}

// ---------------------------------------------------------------------------
__global__ void cast_kernel(const float* __restrict__ in,
                            bf16* __restrict__ out, long long n4) {
  long long i = (long long)blockIdx.x * blockDim.x + threadIdx.x;
  if (i >= n4) return;
  float4 v = ((const float4*)in)[i];
  bf16 a = __float2bfloat16(v.x), b = __float2bfloat16(v.y);
  bf16 c = __float2bfloat16(v.z), d = __float2bfloat16(v.w);
  ushort4 o{__builtin_bit_cast(unsigned short, a), __builtin_bit_cast(unsigned short, b),
            __builtin_bit_cast(unsigned short, c), __builtin_bit_cast(unsigned short, d)};
  ((ushort4*)out)[i] = o;
}

__global__ void cast_pair_kernel(const float* __restrict__ in,
                                 bf16* __restrict__ hi, bf16* __restrict__ lo,
                                 long long n) {
  long long i = (long long)blockIdx.x * blockDim.x + threadIdx.x;
  if (i >= n) return;
  float v = in[i];
  bf16 h = __float2bfloat16(v);
  hi[i] = h;
  lo[i] = __float2bfloat16(v - __bfloat162float(h));
}

__global__ void ln_kernel(const float* __restrict__ in, bf16* __restrict__ out) {
  const int row = blockIdx.x;
  const int tid = threadIdx.x;          // 256
  const float4 v = ((const float4*)(in + (size_t)row*DIM))[tid];
  float s  = v.x + v.y + v.z + v.w;
  float s2 = v.x*v.x + v.y*v.y + v.z*v.z + v.w*v.w;
#pragma unroll
  for (int o = 32; o > 0; o >>= 1) { s += __shfl_xor(s, o); s2 += __shfl_xor(s2, o); }
  __shared__ float red[8];
  const int wv = tid >> 6;
  if ((tid & 63) == 0) { red[wv] = s; red[4 + wv] = s2; }
  __syncthreads();
  s  = red[0] + red[1] + red[2] + red[3];
  s2 = red[4] + red[5] + red[6] + red[7];
  const float mean = s * (1.f / DIM);
  const float var  = s2 * (1.f / DIM) - mean * mean;
  const float inv  = rsqrtf(var + 1e-5f);
  long long base = (long long)row*DIM + tid*4;
  wpair(out, base + 0, PQKV, (v.x - mean) * inv);
  wpair(out, base + 1, PQKV, (v.y - mean) * inv);
  wpair(out, base + 2, PQKV, (v.z - mean) * inv);
  wpair(out, base + 3, PQKV, (v.w - mean) * inv);
}

// q,k pairs [B,L,H*DQ] -> qrot/krot/qwb pairs [B,H,L,2*DQ]
__global__ void rotate_kernel(const bf16* __restrict__ q, const bf16* __restrict__ k,
                              const float* __restrict__ pre, const float* __restrict__ pim,
                              const float* __restrict__ amp,
                              bf16* __restrict__ qrot, bf16* __restrict__ krot,
                              bf16* __restrict__ qwb) {
  const int d = threadIdx.x, l = blockIdx.x, h = blockIdx.y, b = blockIdx.z;
  const float tr = pre[h*DQ + d], ti = pim[h*DQ + d];
  const float theta = atan2f(ti, tr);
  const float a = 1.f / (1.f + __expf(-amp[h]));
  const long long src = ((long long)(b*SEQ + l)*NH + h)*DQ + d;
  const float qv = __bfloat162float(q[src]) + __bfloat162float(q[src + PQKV]);
  const float kv = __bfloat162float(k[src]) + __bfloat162float(k[src + PQKV]);
  float sn, cs;
  sincosf(theta * (float)l, &sn, &cs);
  const long long dst = ((long long)(b*NH + h)*SEQ + l)*(2*DQ) + d;
  wpair(qrot, dst,      PROT, qv * cs);
  wpair(qrot, dst + DQ, PROT, qv * sn);
  wpair(krot, dst,      PROT, kv * cs);
  wpair(krot, dst + DQ, PROT, kv * sn);
  float sn2, cs2;
  sincosf(theta * (float)(l + 1), &sn2, &cs2);
  const float ad = powf(a, (float)(l + 1));
  wpair(qwb, dst,      PROT, qv * ad * cs2);
  wpair(qwb, dst + DQ, PROT, qv * ad * sn2);
}

// v pair [B,L,H*DQ] -> vt pair [B,H,DQ,L]
__global__ void vt_kernel(const bf16* __restrict__ v, bf16* __restrict__ vt) {
  const int d = threadIdx.x, m = blockIdx.x, h = blockIdx.y, b = blockIdx.z;
  const long long src = ((long long)(b*SEQ + m)*NH + h)*DQ + d;
  const long long dst = ((long long)(b*NH + h)*DQ + d)*SEQ + m;
  vt[dst]       = v[src];
  vt[dst + PVT] = v[src + PQKV];
}

// ret [B,H,L,DQ] f32 -> y pair [B,L,H*DQ] with silu
__global__ void siluret_kernel(const float* __restrict__ ret, bf16* __restrict__ y) {
  const int d = threadIdx.x, l = blockIdx.x, h = blockIdx.y, b = blockIdx.z;
  float r = ret[((long long)(b*NH + h)*SEQ + l)*DQ + d];
  float s = r / (1.f + __expf(-r));
  wpair(y, ((long long)(b*SEQ + l)*NH + h)*DQ + d, PY, s);
}

// lc_re/lc_im [H,DQ,DQ] -> lcc pair [H, e, 2*DQ] = [lcr[d,e] ; -lci[d,e]]
__global__ void lccat_kernel(const float* __restrict__ lcr, const float* __restrict__ lci,
                             bf16* __restrict__ lc) {
  const int d = threadIdx.x, e = blockIdx.x, h = blockIdx.y;
  float vr = lcr[((long long)h*DQ + d)*DQ + e];
  float vi = lci[((long long)h*DQ + d)*DQ + e];
  long long dst = ((long long)h*DQ + e)*(2*DQ) + d;
  wpair(lc, dst,      PLC, vr);
  wpair(lc, dst + DQ, PLC, -vi);
}

// ---------------------------------------------------------------------------
extern "C" void kernel_launch(void* const* d_in, const int* in_sizes, int n_in,
                              void* d_out, int out_size, void* d_ws, size_t ws_size,
                              hipStream_t stream) {
  const float* x      = (const float*)d_in[0];
  const float* tin_w  = (const float*)d_in[1];
  const float* tin_b  = (const float*)d_in[2];
  const float* tout_w = (const float*)d_in[3];
  const float* tout_b = (const float*)d_in[4];
  const float* wq_w   = (const float*)d_in[5];
  const float* wq_b   = (const float*)d_in[6];
  const float* wk_w   = (const float*)d_in[7];
  const float* wk_b   = (const float*)d_in[8];
  const float* wv_w   = (const float*)d_in[9];
  const float* wv_b   = (const float*)d_in[10];
  const float* wo_w   = (const float*)d_in[11];
  const float* wo_b   = (const float*)d_in[12];
  const float* f1_w   = (const float*)d_in[13];
  const float* f1_b   = (const float*)d_in[14];
  const float* f2_w   = (const float*)d_in[15];
  const float* f2_b   = (const float*)d_in[16];
  const float* phz_re = (const float*)d_in[17];
  const float* phz_im = (const float*)d_in[18];
  const float* amp    = (const float*)d_in[19];
  const float* lc_re  = (const float*)d_in[20];
  const float* lc_im  = (const float*)d_in[21];
  (void)in_sizes; (void)n_in; (void)out_size; (void)ws_size;

  char* w = (char*)d_ws;
  auto alloc = [&](size_t bytes) {
    char* p = w; w += (bytes + 255) & ~(size_t)255; return p;
  };
  auto palloc = [&](long long elems) {       // hi/lo pair, lo at +elems
    return (bf16*)alloc((size_t)elems * 2 * 2);
  };

  float* h    = (float*)alloc((size_t)ROWS*DIM*4);
  bf16*  hb   = palloc(PQKV);
  bf16*  Wql  = palloc((long long)DIM*DIM);
  bf16*  Wkl  = palloc((long long)DIM*DIM);
  bf16*  Wvl  = palloc((long long)DIM*DIM);
  bf16*  Wol  = palloc((long long)DIM*DIM);
  bf16*  Wf1l = palloc((long long)DH*DIM);
  bf16*  Wf2l = palloc((long long)DIM*DH);
  bf16*  qb   = palloc(PQKV);
  bf16*  kb   = palloc(PQKV);
  bf16*  vb   = palloc(PQKV);
  bf16*  lcc  = palloc(PLC);
  bf16*  Wbig = (bf16*)alloc((size_t)DIM*VOC*2);     // hi plane (tin + tout)
  bf16*  qrot = palloc(PROT);
  bf16*  krot = palloc(PROT);
  bf16*  qwb  = palloc(PROT);
  bf16*  vtb  = palloc(PVT);
  char*  s2   = w;                                   // Wbig_lo aliases here at the end
  bf16*  Sb   = palloc(PS);
  bf16*  mid  = palloc(PMID);
  // aliases (lifetimes disjoint):
  bf16*  xb      = (bf16*)d_out;        // bf16 x (131 MB) in d_out, dead before tout
  bf16*  Wbig_lo = (bf16*)s2;           // tout_w lo plane; Sb/mid dead by then
  float* ret     = (float*)kb;          // PV output; kb dead after rotate
  bf16*  yb      = qb;                  // silu(ret) pair; qb dead after rotate

  auto cast = [&](const float* in, bf16* out, long long n) {
    long long n4 = n / 4;
    cast_kernel<<<dim3((unsigned)((n4 + 255) / 256)), dim3(256), 0, stream>>>(in, out, n4);
  };
  auto cast_pair = [&](const float* in, bf16* hi, bf16* lo, long long n) {
    cast_pair_kernel<<<dim3((unsigned)((n + 255) / 256)), dim3(256), 0, stream>>>(in, hi, lo, n);
  };

  auto gemm = [&](int epi, int split, const bf16* A, long long sA, long long pA, int lda,
                  const bf16* B, long long sB, long long pB, int ldb, int bmod,
                  void* C, long long sC, long long pC, int ldc,
                  const float* bias, int hmod, int M, int N, int K, int batch) {
    dim3 g(N / BN, M / BM, batch), blk(256);
    if (!split)         gemm_bt<0,0,0><<<g, blk, 0, stream>>>(A,sA,pA,lda,B,sB,pB,ldb,bmod,C,sC,pC,ldc,bias,hmod,M,N,K);
    else if (epi == 0)  gemm_bt<0,1,1><<<g, blk, 0, stream>>>(A,sA,pA,lda,B,sB,pB,ldb,bmod,C,sC,pC,ldc,bias,hmod,M,N,K);
    else if (epi == 3)  gemm_bt<3,1,1><<<g, blk, 0, stream>>>(A,sA,pA,lda,B,sB,pB,ldb,bmod,C,sC,pC,ldc,bias,hmod,M,N,K);
    else if (epi == 5)  gemm_bt<5,1,1><<<g, blk, 0, stream>>>(A,sA,pA,lda,B,sB,pB,ldb,bmod,C,sC,pC,ldc,bias,hmod,M,N,K);
    else if (epi == 6)  gemm_bt<6,1,1><<<g, blk, 0, stream>>>(A,sA,pA,lda,B,sB,pB,ldb,bmod,C,sC,pC,ldc,bias,hmod,M,N,K);
    else                gemm_bt<7,1,1><<<g, blk, 0, stream>>>(A,sA,pA,lda,B,sB,pB,ldb,bmod,C,sC,pC,ldc,bias,hmod,M,N,K);
  };
  const int BIG = 1 << 30;

  // ---- input projection (plain bf16: h0 ~ O(1), rounding harmless) ----
  cast(x, xb, (long long)ROWS*VOC);
  cast(tin_w, Wbig, (long long)DIM*VOC);
  gemm(0, 0, xb, 0, 0, VOC, Wbig, 0, 0, VOC, BIG, h, 0, 0, DIM, tin_b, 1, ROWS, DIM, VOC, 1);

  for (int i = 0; i < DEPTH; ++i) {
    cast_pair(wq_w + (size_t)i*DIM*DIM, Wql, Wql + (long long)DIM*DIM, (long long)DIM*DIM);
    cast_pair(wk_w + (size_t)i*DIM*DIM, Wkl, Wkl + (long long)DIM*DIM, (long long)DIM*DIM);
    cast_pair(wv_w + (size_t)i*DIM*DIM, Wvl, Wvl + (long long)DIM*DIM, (long long)DIM*DIM);
    cast_pair(wo_w + (size_t)i*DIM*DIM, Wol, Wol + (long long)DIM*DIM, (long long)DIM*DIM);
    cast_pair(f1_w + (size_t)i*DH*DIM,  Wf1l, Wf1l + (long long)DH*DIM, (long long)DH*DIM);
    cast_pair(f2_w + (size_t)i*DIM*DH,  Wf2l, Wf2l + (long long)DIM*DH, (long long)DIM*DH);

    // retention
    ln_kernel<<<ROWS, 256, 0, stream>>>(h, hb);
    gemm(5, 1, hb, 0, PQKV, DIM, Wql, 0, (long long)DIM*DIM, DIM, BIG,
         qb, 0, PQKV, DIM, wq_b + i*DIM, 1, ROWS, DIM, DIM, 1);
    gemm(5, 1, hb, 0, PQKV, DIM, Wkl, 0, (long long)DIM*DIM, DIM, BIG,
         kb, 0, PQKV, DIM, wk_b + i*DIM, 1, ROWS, DIM, DIM, 1);
    gemm(5, 1, hb, 0, PQKV, DIM, Wvl, 0, (long long)DIM*DIM, DIM, BIG,
         vb, 0, PQKV, DIM, wv_b + i*DIM, 1, ROWS, DIM, DIM, 1);
    rotate_kernel<<<dim3(SEQ, NH, BATCH), DQ, 0, stream>>>(
        qb, kb, phz_re + i*NH*DQ, phz_im + i*NH*DQ, amp + i*NH, qrot, krot, qwb);
    vt_kernel<<<dim3(SEQ, NH, BATCH), DQ, 0, stream>>>(vb, vtb);
    lccat_kernel<<<dim3(DQ, NH), DQ, 0, stream>>>(
        lc_re + (size_t)i*NH*DQ*DQ, lc_im + (size_t)i*NH*DQ*DQ, lcc);
    // S = (Qrot Krot^T) * decay-mask
    gemm(7, 1, qrot, (long long)SEQ*2*DQ, PROT, 2*DQ,
         krot, (long long)SEQ*2*DQ, PROT, 2*DQ, BIG,
         Sb, (long long)SEQ*SEQ, PS, SEQ, amp + i*NH, NH, SEQ, SEQ, 2*DQ, BATCH*NH);
    // ret = S @ V
    gemm(0, 1, Sb, (long long)SEQ*SEQ, PS, SEQ,
         vtb, (long long)DQ*SEQ, PVT, SEQ, BIG,
         ret, (long long)SEQ*DQ, 0, DQ, nullptr, 1, SEQ, DQ, SEQ, BATCH*NH);
    // ret += cross
    gemm(3, 1, qwb, (long long)SEQ*2*DQ, PROT, 2*DQ,
         lcc, (long long)DQ*2*DQ, PLC, 2*DQ, NH,
         ret, (long long)SEQ*DQ, 0, DQ, nullptr, 1, SEQ, DQ, 2*DQ, BATCH*NH);
    siluret_kernel<<<dim3(SEQ, NH, BATCH), DQ, 0, stream>>>(ret, yb);
    // h += y @ wo^T + wo_b
    gemm(3, 1, yb, 0, PY, DIM, Wol, 0, (long long)DIM*DIM, DIM, BIG,
         h, 0, 0, DIM, wo_b + i*DIM, 1, ROWS, DIM, DIM, 1);

    // FFN
    ln_kernel<<<ROWS, 256, 0, stream>>>(h, hb);
    gemm(6, 1, hb, 0, PQKV, DIM, Wf1l, 0, (long long)DH*DIM, DIM, BIG,
         mid, 0, PMID, DH, f1_b + i*DH, 1, ROWS, DH, DIM, 1);
    gemm(3, 1, mid, 0, PMID, DH, Wf2l, 0, (long long)DIM*DH, DH, BIG,
         h, 0, 0, DIM, f2_b + i*DIM, 1, ROWS, DIM, DH, 1);
  }

  // ---- output projection (split both operands; Sb/mid dead -> Wbig_lo alias) ----
  cast_pair(h, hb, hb + PQKV, PQKV);
  cast_pair(tout_w, Wbig, Wbig_lo, (long long)VOC*DIM);
  gemm(0, 1, hb, 0, PQKV, DIM, Wbig, 0, (long long)(Wbig_lo - Wbig), DIM, BIG,
       (float*)d_out, 0, 0, VOC, tout_b, 1, ROWS, VOC, DIM, 1);
}

// Round 3
// 2736.879 us; speedup vs baseline: 1.3487x; 1.3487x over previous
//
#include <hip/hip_runtime.h>
#include <hip/hip_bf16.h>
#include <stdint.h>

#define DEPTH 4
#define DIM   1024
#define DH    4096
#define NH    8
#define DQ    128
#define VOC   32000
#define BATCH 2
#define SEQ   1024
#define ROWS  (BATCH*SEQ)   // 2048

#define PQKV  ((long long)ROWS*DIM)
#define PQKV3 ((long long)ROWS*3*DIM)
#define PROT  ((long long)BATCH*NH*SEQ*2*DQ)
#define PVT   ((long long)BATCH*NH*DQ*SEQ)
#define PS    ((long long)BATCH*NH*SEQ*SEQ)
#define PMID  ((long long)ROWS*DH)
#define PY    ((long long)ROWS*DIM)
#define PLC   ((long long)NH*DQ*2*DQ)

typedef __hip_bfloat16 bf16;
using f32x4  = __attribute__((ext_vector_type(4))) float;
using bf16x8 = __attribute__((ext_vector_type(8))) __bf16;

__device__ __forceinline__ void wpair(bf16* p, long long off, long long plane, float v) {
  bf16 hi = __float2bfloat16(v);
  p[off] = hi;
  p[off + plane] = __float2bfloat16(v - __bfloat162float(hi));
}

__device__ __forceinline__ void gload_lds16(const void* g, void* l) {
  __builtin_amdgcn_global_load_lds(
      (const __attribute__((address_space(1))) void*)g,
      (__attribute__((address_space(3))) void*)(uintptr_t)l,
      16, 0, 0);
}

// ---------------------------------------------------------------------------
// Batched GEMM: C[zb] = A[zb] (MxK rm) * B[zb%bmod]^T (NxK rm)
// blockIdx.z = zb*ksplit + kslice; each slice covers Kc=K/ksplit columns.
// SA/SB: bf16 hi/lo pair operand (lo plane at +pA/+pB); 3-pass compensated.
// EPI 0: f32 C = acc+bias              3: f32 C += acc+bias (atomic if ksplit>1)
//     5: pair C = acc+bias             6: pair C = silu(acc+bias)
//     7: pair C = acc*decay, decay=a^(row-col) (row>=col), a=sigmoid(bias[zb%hmod])
// bias added by slice 0 only.
// ---------------------------------------------------------------------------
#define BM 128
#define BN 128
#define BKK 64
#define PL 16384   // one LDS plane: 128 rows x 64 bf16

template<int EPI, int SA, int SB>
__global__ __launch_bounds__(256, (SA || SB) ? 2 : 4)
void gemm_bt(const bf16* __restrict__ A, long long sA, long long pA, int lda,
             const bf16* __restrict__ B, long long sB, long long pB, int ldb, int bmod,
             void* __restrict__ Cv, long long sC, long long pC, int ldc,
             const float* __restrict__ bias, int hmod,
             int M, int N, int K, int ksplit)
{
  __shared__ int4 sbuf[1024 * (2 + SA + SB)];
  char* Asb = (char*)sbuf;
  char* Bsb = Asb + PL * (1 + SA);

  const int tid  = threadIdx.x;
  const int lane = tid & 63;
  const int wave = tid >> 6;
  const int wr   = wave >> 1;
  const int wc   = wave & 1;
  const int z    = blockIdx.z;
  const int zb   = z / ksplit;
  const int ks   = z - zb * ksplit;
  const int Kc   = K / ksplit;
  const int k0   = ks * Kc;
  const long long tm = (long long)blockIdx.y * BM;
  const long long tn = (long long)blockIdx.x * BN;

  const bf16* Ab = A + (long long)zb * sA;
  const bf16* Bb = B + (long long)(zb % bmod) * sB;

  f32x4 acc[4][4] = {};

  for (int kt = k0; kt < k0 + Kc; kt += BKK) {
#pragma unroll
    for (int j = 0; j < 4; ++j) {
      int slot0 = j*256 + wave*64;          // wave-uniform LDS base
      int i = slot0 + lane;
      int row = i >> 3;
      int gc  = (i & 7) ^ (row & 7);        // inverse-swizzled global chunk
      long long ga = (tm + row) * (long long)lda + kt + gc*8;
      long long gb = (tn + row) * (long long)ldb + kt + gc*8;
      gload_lds16(Ab + ga, Asb + slot0*16);
      if (SA) gload_lds16(Ab + pA + ga, Asb + PL + slot0*16);
      gload_lds16(Bb + gb, Bsb + slot0*16);
      if (SB) gload_lds16(Bb + pB + gb, Bsb + PL + slot0*16);
    }
    __syncthreads();
#pragma unroll
    for (int kh = 0; kh < 2; ++kh) {
      const int cb = kh*4 + (lane >> 4);
      int4 avh[4], bvh[4], avl[4], bvl[4];
#pragma unroll
      for (int mi = 0; mi < 4; ++mi) {
        int m = wr*64 + mi*16 + (lane & 15);
        int off = m*128 + ((cb ^ (m & 7)) << 4);
        avh[mi] = *(const int4*)(Asb + off);
        if (SA) avl[mi] = *(const int4*)(Asb + PL + off);
      }
#pragma unroll
      for (int nj = 0; nj < 4; ++nj) {
        int n = wc*64 + nj*16 + (lane & 15);
        int off = n*128 + ((cb ^ (n & 7)) << 4);
        bvh[nj] = *(const int4*)(Bsb + off);
        if (SB) bvl[nj] = *(const int4*)(Bsb + PL + off);
      }
#pragma unroll
      for (int mi = 0; mi < 4; ++mi)
#pragma unroll
        for (int nj = 0; nj < 4; ++nj)
          acc[mi][nj] = __builtin_amdgcn_mfma_f32_16x16x32_bf16(
              __builtin_bit_cast(bf16x8, avh[mi]),
              __builtin_bit_cast(bf16x8, bvh[nj]), acc[mi][nj], 0, 0, 0);
      if (SA)
#pragma unroll
        for (int mi = 0; mi < 4; ++mi)
#pragma unroll
          for (int nj = 0; nj < 4; ++nj)
            acc[mi][nj] = __builtin_amdgcn_mfma_f32_16x16x32_bf16(
                __builtin_bit_cast(bf16x8, avl[mi]),
                __builtin_bit_cast(bf16x8, bvh[nj]), acc[mi][nj], 0, 0, 0);
      if (SB)
#pragma unroll
        for (int mi = 0; mi < 4; ++mi)
#pragma unroll
          for (int nj = 0; nj < 4; ++nj)
            acc[mi][nj] = __builtin_amdgcn_mfma_f32_16x16x32_bf16(
                __builtin_bit_cast(bf16x8, avh[mi]),
                __builtin_bit_cast(bf16x8, bvl[nj]), acc[mi][nj], 0, 0, 0);
    }
    __syncthreads();
  }

  float aa = 0.f;
  if (EPI == 7) aa = 1.f / (1.f + __expf(-bias[zb % hmod]));
  const int col = lane & 15;
  const int rb  = (lane >> 4) << 2;
  float* Cf = (float*)Cv + (long long)zb * sC;
  bf16*  Ch = (bf16*) Cv + (long long)zb * sC;

#pragma unroll
  for (int mi = 0; mi < 4; ++mi)
#pragma unroll
    for (int nj = 0; nj < 4; ++nj) {
      long long gn = tn + wc*64 + nj*16 + col;
      float bv_ = (EPI != 7 && bias && ks == 0) ? bias[gn] : 0.f;
#pragma unroll
      for (int r = 0; r < 4; ++r) {
        long long gm = tm + wr*64 + mi*16 + rb + r;
        float v = acc[mi][nj][r] + bv_;
        long long off = gm * (long long)ldc + gn;
        if (EPI == 0)      Cf[off] = v;
        else if (EPI == 3) { if (ksplit > 1) atomicAdd(&Cf[off], v); else Cf[off] += v; }
        else if (EPI == 5) wpair(Ch, off, pC, v);
        else if (EPI == 6) wpair(Ch, off, pC, v / (1.f + __expf(-v)));
        else {
          long long dlt = gm - gn;
          float dcy = (dlt >= 0) ? powf(aa, (float)dlt) : 0.f;
          wpair(Ch, off, pC, acc[mi][nj][r] * dcy);
        }
      }
    }
}

// ---------------------------------------------------------------------------
__global__ void zero_kernel(float4* __restrict__ p, long long n4) {
  long long i = (long long)blockIdx.x * blockDim.x + threadIdx.x;
  if (i < n4) p[i] = float4{0.f, 0.f, 0.f, 0.f};
}

__global__ void cast_kernel(const float* __restrict__ in,
                            bf16* __restrict__ out, long long n4) {
  long long i = (long long)blockIdx.x * blockDim.x + threadIdx.x;
  if (i >= n4) return;
  float4 v = ((const float4*)in)[i];
  bf16 a = __float2bfloat16(v.x), b = __float2bfloat16(v.y);
  bf16 c = __float2bfloat16(v.z), d = __float2bfloat16(v.w);
  ushort4 o{__builtin_bit_cast(unsigned short, a), __builtin_bit_cast(unsigned short, b),
            __builtin_bit_cast(unsigned short, c), __builtin_bit_cast(unsigned short, d)};
  ((ushort4*)out)[i] = o;
}

__global__ void cast_pair_kernel(const float* __restrict__ in,
                                 bf16* __restrict__ hi, bf16* __restrict__ lo,
                                 long long n) {
  long long i = (long long)blockIdx.x * blockDim.x + threadIdx.x;
  if (i >= n) return;
  float v = in[i];
  bf16 h = __float2bfloat16(v);
  hi[i] = h;
  lo[i] = __float2bfloat16(v - __bfloat162float(h));
}

__global__ void bias3_kernel(const float* __restrict__ q, const float* __restrict__ k,
                             const float* __restrict__ v, float* __restrict__ o) {
  int i = blockIdx.x * blockDim.x + threadIdx.x;
  if (i < DIM) o[i] = q[i];
  else if (i < 2*DIM) o[i] = k[i - DIM];
  else if (i < 3*DIM) o[i] = v[i - 2*DIM];
}

__global__ void ln_kernel(const float* __restrict__ in, bf16* __restrict__ out) {
  const int row = blockIdx.x;
  const int tid = threadIdx.x;          // 256
  const float4 v = ((const float4*)(in + (size_t)row*DIM))[tid];
  float s  = v.x + v.y + v.z + v.w;
  float s2 = v.x*v.x + v.y*v.y + v.z*v.z + v.w*v.w;
#pragma unroll
  for (int o = 32; o > 0; o >>= 1) { s += __shfl_xor(s, o); s2 += __shfl_xor(s2, o); }
  __shared__ float red[8];
  const int wv = tid >> 6;
  if ((tid & 63) == 0) { red[wv] = s; red[4 + wv] = s2; }
  __syncthreads();
  s  = red[0] + red[1] + red[2] + red[3];
  s2 = red[4] + red[5] + red[6] + red[7];
  const float mean = s * (1.f / DIM);
  const float var  = s2 * (1.f / DIM) - mean * mean;
  const float inv  = rsqrtf(var + 1e-5f);
  long long base = (long long)row*DIM + tid*4;
  wpair(out, base + 0, PQKV, (v.x - mean) * inv);
  wpair(out, base + 1, PQKV, (v.y - mean) * inv);
  wpair(out, base + 2, PQKV, (v.z - mean) * inv);
  wpair(out, base + 3, PQKV, (v.w - mean) * inv);
}

// qkv pair [B,L,3*DIM] -> qrot/krot/qwb pairs [B,H,L,2*DQ]
__global__ void rotate_kernel(const bf16* __restrict__ qkv,
                              const float* __restrict__ pre, const float* __restrict__ pim,
                              const float* __restrict__ amp,
                              bf16* __restrict__ qrot, bf16* __restrict__ krot,
                              bf16* __restrict__ qwb) {
  const int d = threadIdx.x, l = blockIdx.x, h = blockIdx.y, b = blockIdx.z;
  const float tr = pre[h*DQ + d], ti = pim[h*DQ + d];
  const float theta = atan2f(ti, tr);
  const float a = 1.f / (1.f + __expf(-amp[h]));
  const long long rowb = (long long)(b*SEQ + l)*(3*DIM) + h*DQ + d;
  const float qv = __bfloat162float(qkv[rowb]) + __bfloat162float(qkv[rowb + PQKV3]);
  const float kv = __bfloat162float(qkv[rowb + DIM]) + __bfloat162float(qkv[rowb + DIM + PQKV3]);
  float sn, cs;
  sincosf(theta * (float)l, &sn, &cs);
  const long long dst = ((long long)(b*NH + h)*SEQ + l)*(2*DQ) + d;
  wpair(qrot, dst,      PROT, qv * cs);
  wpair(qrot, dst + DQ, PROT, qv * sn);
  wpair(krot, dst,      PROT, kv * cs);
  wpair(krot, dst + DQ, PROT, kv * sn);
  float sn2, cs2;
  sincosf(theta * (float)(l + 1), &sn2, &cs2);
  const float ad = powf(a, (float)(l + 1));
  wpair(qwb, dst,      PROT, qv * ad * cs2);
  wpair(qwb, dst + DQ, PROT, qv * ad * sn2);
}

// v (inside qkv pair) -> vt pair [B,H,DQ,L]
__global__ void vt_kernel(const bf16* __restrict__ qkv, bf16* __restrict__ vt) {
  const int d = threadIdx.x, m = blockIdx.x, h = blockIdx.y, b = blockIdx.z;
  const long long src = (long long)(b*SEQ + m)*(3*DIM) + 2*DIM + h*DQ + d;
  const long long dst = ((long long)(b*NH + h)*DQ + d)*SEQ + m;
  vt[dst]       = qkv[src];
  vt[dst + PVT] = qkv[src + PQKV3];
}

// ret [B,H,L,DQ] f32 -> y pair [B,L,H*DQ] with silu
__global__ void siluret_kernel(const float* __restrict__ ret, bf16* __restrict__ y) {
  const int d = threadIdx.x, l = blockIdx.x, h = blockIdx.y, b = blockIdx.z;
  float r = ret[((long long)(b*NH + h)*SEQ + l)*DQ + d];
  float s = r / (1.f + __expf(-r));
  wpair(y, ((long long)(b*SEQ + l)*NH + h)*DQ + d, PY, s);
}

// lc_re/lc_im [H,DQ,DQ] -> lcc pair [H, e, 2*DQ] = [lcr[d,e] ; -lci[d,e]]
__global__ void lccat_kernel(const float* __restrict__ lcr, const float* __restrict__ lci,
                             bf16* __restrict__ lc) {
  const int d = threadIdx.x, e = blockIdx.x, h = blockIdx.y;
  float vr = lcr[((long long)h*DQ + d)*DQ + e];
  float vi = lci[((long long)h*DQ + d)*DQ + e];
  long long dst = ((long long)h*DQ + e)*(2*DQ) + d;
  wpair(lc, dst,      PLC, vr);
  wpair(lc, dst + DQ, PLC, -vi);
}

// ---------------------------------------------------------------------------
extern "C" void kernel_launch(void* const* d_in, const int* in_sizes, int n_in,
                              void* d_out, int out_size, void* d_ws, size_t ws_size,
                              hipStream_t stream) {
  const float* x      = (const float*)d_in[0];
  const float* tin_w  = (const float*)d_in[1];
  const float* tin_b  = (const float*)d_in[2];
  const float* tout_w = (const float*)d_in[3];
  const float* tout_b = (const float*)d_in[4];
  const float* wq_w   = (const float*)d_in[5];
  const float* wq_b   = (const float*)d_in[6];
  const float* wk_w   = (const float*)d_in[7];
  const float* wk_b   = (const float*)d_in[8];
  const float* wv_w   = (const float*)d_in[9];
  const float* wv_b   = (const float*)d_in[10];
  const float* wo_w   = (const float*)d_in[11];
  const float* wo_b   = (const float*)d_in[12];
  const float* f1_w   = (const float*)d_in[13];
  const float* f1_b   = (const float*)d_in[14];
  const float* f2_w   = (const float*)d_in[15];
  const float* f2_b   = (const float*)d_in[16];
  const float* phz_re = (const float*)d_in[17];
  const float* phz_im = (const float*)d_in[18];
  const float* amp    = (const float*)d_in[19];
  const float* lc_re  = (const float*)d_in[20];
  const float* lc_im  = (const float*)d_in[21];
  (void)in_sizes; (void)n_in; (void)out_size; (void)ws_size;

  char* w = (char*)d_ws;
  auto alloc = [&](size_t bytes) {
    char* p = w; w += (bytes + 255) & ~(size_t)255; return p;
  };
  auto palloc = [&](long long elems) {       // hi/lo pair, lo at +elems
    return (bf16*)alloc((size_t)elems * 2 * 2);
  };

  const long long WP = 3LL*DIM*DIM;          // fused qkv weight plane
  float* h     = (float*)alloc((size_t)ROWS*DIM*4);
  float* ret   = (float*)alloc((size_t)BATCH*NH*SEQ*DQ*4);
  float* qkvbi = (float*)alloc((size_t)3*DIM*4);
  bf16*  hb    = palloc(PQKV);
  bf16*  Wqkv  = palloc(WP);
  bf16*  Wol   = palloc((long long)DIM*DIM);
  bf16*  Wf1l  = palloc((long long)DH*DIM);
  bf16*  Wf2l  = palloc((long long)DIM*DH);
  bf16*  qkvb  = palloc(PQKV3);
  bf16*  lcc   = palloc(PLC);
  bf16*  Wbig  = (bf16*)alloc((size_t)DIM*VOC*2);     // hi plane (tin + tout)
  bf16*  qrot  = palloc(PROT);
  bf16*  krot  = palloc(PROT);
  bf16*  qwb   = palloc(PROT);
  bf16*  vtb   = palloc(PVT);
  char*  s2    = w;                                   // Wbig_lo aliases here at end
  bf16*  Sb    = palloc(PS);
  bf16*  mid   = palloc(PMID);
  // aliases (lifetimes disjoint):
  bf16*  xb      = (bf16*)d_out;    // bf16 x in d_out; dead before tout writes
  bf16*  Wbig_lo = (bf16*)s2;       // tout_w lo plane; Sb/mid dead by then
  bf16*  yb      = qkvb;            // silu(ret) pair; qkvb dead after rotate/vt

  auto cast = [&](const float* in, bf16* out, long long n) {
    long long n4 = n / 4;
    cast_kernel<<<dim3((unsigned)((n4 + 255) / 256)), dim3(256), 0, stream>>>(in, out, n4);
  };
  auto cast_pair = [&](const float* in, bf16* hi, bf16* lo, long long n) {
    cast_pair_kernel<<<dim3((unsigned)((n + 255) / 256)), dim3(256), 0, stream>>>(in, hi, lo, n);
  };
  auto zero = [&](float* p, long long nfloats) {
    long long n4 = nfloats / 4;
    zero_kernel<<<dim3((unsigned)((n4 + 255) / 256)), dim3(256), 0, stream>>>((float4*)p, n4);
  };

  auto gemm = [&](int epi, int split, const bf16* A, long long sA, long long pA, int lda,
                  const bf16* B, long long sB, long long pB, int ldb, int bmod,
                  void* C, long long sC, long long pC, int ldc,
                  const float* bias, int hmod, int M, int N, int K, int batch, int ksplit) {
    dim3 g(N / BN, M / BM, batch * ksplit), blk(256);
    if (!split) {
      if (epi == 0) gemm_bt<0,0,0><<<g, blk, 0, stream>>>(A,sA,pA,lda,B,sB,pB,ldb,bmod,C,sC,pC,ldc,bias,hmod,M,N,K,ksplit);
      else          gemm_bt<3,0,0><<<g, blk, 0, stream>>>(A,sA,pA,lda,B,sB,pB,ldb,bmod,C,sC,pC,ldc,bias,hmod,M,N,K,ksplit);
    }
    else if (epi == 0) gemm_bt<0,1,1><<<g, blk, 0, stream>>>(A,sA,pA,lda,B,sB,pB,ldb,bmod,C,sC,pC,ldc,bias,hmod,M,N,K,ksplit);
    else if (epi == 3) gemm_bt<3,1,1><<<g, blk, 0, stream>>>(A,sA,pA,lda,B,sB,pB,ldb,bmod,C,sC,pC,ldc,bias,hmod,M,N,K,ksplit);
    else if (epi == 5) gemm_bt<5,1,1><<<g, blk, 0, stream>>>(A,sA,pA,lda,B,sB,pB,ldb,bmod,C,sC,pC,ldc,bias,hmod,M,N,K,ksplit);
    else if (epi == 6) gemm_bt<6,1,1><<<g, blk, 0, stream>>>(A,sA,pA,lda,B,sB,pB,ldb,bmod,C,sC,pC,ldc,bias,hmod,M,N,K,ksplit);
    else               gemm_bt<7,1,1><<<g, blk, 0, stream>>>(A,sA,pA,lda,B,sB,pB,ldb,bmod,C,sC,pC,ldc,bias,hmod,M,N,K,ksplit);
  };
  const int BIG = 1 << 30;

  // ---- input projection: h = x @ tin_w^T + tin_b  (split-K x10, atomic) ----
  cast(x, xb, (long long)ROWS*VOC);
  cast(tin_w, Wbig, (long long)DIM*VOC);
  zero(h, (long long)ROWS*DIM);
  gemm(3, 0, xb, 0, 0, VOC, Wbig, 0, 0, VOC, BIG, h, 0, 0, DIM, tin_b, 1,
       ROWS, DIM, VOC, 1, 10);

  for (int i = 0; i < DEPTH; ++i) {
    cast_pair(wq_w + (size_t)i*DIM*DIM, Wqkv,             Wqkv + WP,             (long long)DIM*DIM);
    cast_pair(wk_w + (size_t)i*DIM*DIM, Wqkv +   DIM*DIM, Wqkv + WP +   DIM*DIM, (long long)DIM*DIM);
    cast_pair(wv_w + (size_t)i*DIM*DIM, Wqkv + 2*DIM*DIM, Wqkv + WP + 2*DIM*DIM, (long long)DIM*DIM);
    cast_pair(wo_w + (size_t)i*DIM*DIM, Wol,  Wol  + (long long)DIM*DIM, (long long)DIM*DIM);
    cast_pair(f1_w + (size_t)i*DH*DIM,  Wf1l, Wf1l + (long long)DH*DIM,  (long long)DH*DIM);
    cast_pair(f2_w + (size_t)i*DIM*DH,  Wf2l, Wf2l + (long long)DIM*DH,  (long long)DIM*DH);
    bias3_kernel<<<dim3(12), dim3(256), 0, stream>>>(
        wq_b + i*DIM, wk_b + i*DIM, wv_b + i*DIM, qkvbi);

    // retention
    ln_kernel<<<ROWS, 256, 0, stream>>>(h, hb);
    // fused qkv = hb @ [Wq;Wk;Wv]^T + [bq;bk;bv]   (N=3072 -> 384 blocks)
    gemm(5, 1, hb, 0, PQKV, DIM, Wqkv, 0, WP, DIM, BIG,
         qkvb, 0, PQKV3, 3*DIM, qkvbi, 1, ROWS, 3*DIM, DIM, 1, 1);
    rotate_kernel<<<dim3(SEQ, NH, BATCH), DQ, 0, stream>>>(
        qkvb, phz_re + i*NH*DQ, phz_im + i*NH*DQ, amp + i*NH, qrot, krot, qwb);
    vt_kernel<<<dim3(SEQ, NH, BATCH), DQ, 0, stream>>>(qkvb, vtb);
    lccat_kernel<<<dim3(DQ, NH), DQ, 0, stream>>>(
        lc_re + (size_t)i*NH*DQ*DQ, lc_im + (size_t)i*NH*DQ*DQ, lcc);
    // S = (Qrot Krot^T) * decay-mask   (1024 blocks)
    gemm(7, 1, qrot, (long long)SEQ*2*DQ, PROT, 2*DQ,
         krot, (long long)SEQ*2*DQ, PROT, 2*DQ, BIG,
         Sb, (long long)SEQ*SEQ, PS, SEQ, amp + i*NH, NH, SEQ, SEQ, 2*DQ, BATCH*NH, 1);
    // ret = S @ V (split-K x4, atomic into zeroed ret) + cross (split-K x2)
    zero(ret, (long long)BATCH*NH*SEQ*DQ);
    gemm(3, 1, Sb, (long long)SEQ*SEQ, PS, SEQ,
         vtb, (long long)DQ*SEQ, PVT, SEQ, BIG,
         ret, (long long)SEQ*DQ, 0, DQ, nullptr, 1, SEQ, DQ, SEQ, BATCH*NH, 4);
    gemm(3, 1, qwb, (long long)SEQ*2*DQ, PROT, 2*DQ,
         lcc, (long long)DQ*2*DQ, PLC, 2*DQ, NH,
         ret, (long long)SEQ*DQ, 0, DQ, nullptr, 1, SEQ, DQ, 2*DQ, BATCH*NH, 2);
    siluret_kernel<<<dim3(SEQ, NH, BATCH), DQ, 0, stream>>>(ret, yb);
    // h += y @ wo^T + wo_b   (split-K x2)
    gemm(3, 1, yb, 0, PY, DIM, Wol, 0, (long long)DIM*DIM, DIM, BIG,
         h, 0, 0, DIM, wo_b + i*DIM, 1, ROWS, DIM, DIM, 1, 2);

    // FFN
    ln_kernel<<<ROWS, 256, 0, stream>>>(h, hb);
    gemm(6, 1, hb, 0, PQKV, DIM, Wf1l, 0, (long long)DH*DIM, DIM, BIG,
         mid, 0, PMID, DH, f1_b + i*DH, 1, ROWS, DH, DIM, 1, 1);
    gemm(3, 1, mid, 0, PMID, DH, Wf2l, 0, (long long)DIM*DH, DH, BIG,
         h, 0, 0, DIM, f2_b + i*DIM, 1, ROWS, DIM, DH, 1, 4);
  }

  // ---- output projection (split both operands; Sb/mid dead -> Wbig_lo alias) ----
  cast_pair(h, hb, hb + PQKV, PQKV);
  cast_pair(tout_w, Wbig, Wbig_lo, (long long)VOC*DIM);
  gemm(0, 1, hb, 0, PQKV, DIM, Wbig, 0, (long long)(Wbig_lo - Wbig), DIM, BIG,
       (float*)d_out, 0, 0, VOC, tout_b, 1, ROWS, VOC, DIM, 1, 1);
}

// Round 4
// 2358.116 us; speedup vs baseline: 1.5654x; 1.1606x over previous
//
#include <hip/hip_runtime.h>
#include <hip/hip_bf16.h>
#include <stdint.h>

#define DEPTH 4
#define DIM   1024
#define DH    4096
#define NH    8
#define DQ    128
#define VOC   32000
#define BATCH 2
#define SEQ   1024
#define ROWS  (BATCH*SEQ)   // 2048

#define PQKV  ((long long)ROWS*DIM)
#define PQKV3 ((long long)ROWS*3*DIM)
#define PROT  ((long long)BATCH*NH*SEQ*2*DQ)
#define PVT   ((long long)BATCH*NH*DQ*SEQ)
#define PS    ((long long)BATCH*NH*SEQ*SEQ)
#define PMID  ((long long)ROWS*DH)
#define PY    ((long long)ROWS*DIM)
#define PLC   ((long long)NH*DQ*2*DQ)

typedef __hip_bfloat16 bf16;
using f32x4  = __attribute__((ext_vector_type(4))) float;
using bf16x8 = __attribute__((ext_vector_type(8))) __bf16;

__device__ __forceinline__ void wpair(bf16* p, long long off, long long plane, float v) {
  bf16 hi = __float2bfloat16(v);
  p[off] = hi;
  p[off + plane] = __float2bfloat16(v - __bfloat162float(hi));
}

__device__ __forceinline__ void gload_lds16(const void* g, void* l) {
  __builtin_amdgcn_global_load_lds(
      (const __attribute__((address_space(1))) void*)g,
      (__attribute__((address_space(3))) void*)(uintptr_t)l,
      16, 0, 0);
}

// ---------------------------------------------------------------------------
// Batched GEMM: C[zb] = A[zb] (MxK rm) * B[zb%bmod]^T (NxK rm)
// Tile map: tm = blockIdx.x (m fastest -> consecutive blocks share B tile),
// tn = blockIdx.y. blockIdx.z = zb*ksplit + kslice (Kc = K/ksplit columns).
// SA/SB: bf16 hi/lo pair operand (lo at +pA/+pB); 3-pass compensated.
// EPI 0: f32 C = acc+bias              3: f32 C += acc+bias (atomic if ksplit>1)
//     5: pair C = acc+bias             6: pair C = silu(acc+bias)
//     7: bf16 C = acc*decay, decay = dtab[head*(SEQ+1) + (row-col)] (row>=col),
//        head = zb%hmod, dtab passed via `bias`.
// bias added by slice 0 only.
// ---------------------------------------------------------------------------
#define BM 128
#define BN 128
#define BKK 64
#define PL 16384   // one LDS plane: 128 rows x 64 bf16

template<int EPI, int SA, int SB>
__global__ __launch_bounds__(256, (SA || SB) ? 2 : 4)
void gemm_bt(const bf16* __restrict__ A, long long sA, long long pA, int lda,
             const bf16* __restrict__ B, long long sB, long long pB, int ldb, int bmod,
             void* __restrict__ Cv, long long sC, long long pC, int ldc,
             const float* __restrict__ bias, int hmod,
             int M, int N, int K, int ksplit)
{
  __shared__ int4 sbuf[1024 * (2 + SA + SB)];
  char* Asb = (char*)sbuf;
  char* Bsb = Asb + PL * (1 + SA);

  const int tid  = threadIdx.x;
  const int lane = tid & 63;
  const int wave = tid >> 6;
  const int wr   = wave >> 1;
  const int wc   = wave & 1;
  const int z    = blockIdx.z;
  const int zb   = z / ksplit;
  const int ks   = z - zb * ksplit;
  const int Kc   = K / ksplit;
  const int k0   = ks * Kc;
  const long long tm = (long long)blockIdx.x * BM;
  const long long tn = (long long)blockIdx.y * BN;

  const bf16* Ab = A + (long long)zb * sA;
  const bf16* Bb = B + (long long)(zb % bmod) * sB;

  f32x4 acc[4][4] = {};

  for (int kt = k0; kt < k0 + Kc; kt += BKK) {
#pragma unroll
    for (int j = 0; j < 4; ++j) {
      int slot0 = j*256 + wave*64;          // wave-uniform LDS base
      int i = slot0 + lane;
      int row = i >> 3;
      int gc  = (i & 7) ^ (row & 7);        // inverse-swizzled global chunk
      long long ga = (tm + row) * (long long)lda + kt + gc*8;
      long long gb = (tn + row) * (long long)ldb + kt + gc*8;
      gload_lds16(Ab + ga, Asb + slot0*16);
      if (SA) gload_lds16(Ab + pA + ga, Asb + PL + slot0*16);
      gload_lds16(Bb + gb, Bsb + slot0*16);
      if (SB) gload_lds16(Bb + pB + gb, Bsb + PL + slot0*16);
    }
    __syncthreads();
#pragma unroll
    for (int kh = 0; kh < 2; ++kh) {
      const int cb = kh*4 + (lane >> 4);
      int4 avh[4], bvh[4], avl[4], bvl[4];
#pragma unroll
      for (int mi = 0; mi < 4; ++mi) {
        int m = wr*64 + mi*16 + (lane & 15);
        int off = m*128 + ((cb ^ (m & 7)) << 4);
        avh[mi] = *(const int4*)(Asb + off);
        if (SA) avl[mi] = *(const int4*)(Asb + PL + off);
      }
#pragma unroll
      for (int nj = 0; nj < 4; ++nj) {
        int n = wc*64 + nj*16 + (lane & 15);
        int off = n*128 + ((cb ^ (n & 7)) << 4);
        bvh[nj] = *(const int4*)(Bsb + off);
        if (SB) bvl[nj] = *(const int4*)(Bsb + PL + off);
      }
#pragma unroll
      for (int mi = 0; mi < 4; ++mi)
#pragma unroll
        for (int nj = 0; nj < 4; ++nj)
          acc[mi][nj] = __builtin_amdgcn_mfma_f32_16x16x32_bf16(
              __builtin_bit_cast(bf16x8, avh[mi]),
              __builtin_bit_cast(bf16x8, bvh[nj]), acc[mi][nj], 0, 0, 0);
      if (SA)
#pragma unroll
        for (int mi = 0; mi < 4; ++mi)
#pragma unroll
          for (int nj = 0; nj < 4; ++nj)
            acc[mi][nj] = __builtin_amdgcn_mfma_f32_16x16x32_bf16(
                __builtin_bit_cast(bf16x8, avl[mi]),
                __builtin_bit_cast(bf16x8, bvh[nj]), acc[mi][nj], 0, 0, 0);
      if (SB)
#pragma unroll
        for (int mi = 0; mi < 4; ++mi)
#pragma unroll
          for (int nj = 0; nj < 4; ++nj)
            acc[mi][nj] = __builtin_amdgcn_mfma_f32_16x16x32_bf16(
                __builtin_bit_cast(bf16x8, avh[mi]),
                __builtin_bit_cast(bf16x8, bvl[nj]), acc[mi][nj], 0, 0, 0);
    }
    __syncthreads();
  }

  const float* dtab = (EPI == 7) ? bias + (zb % hmod) * (SEQ + 1) : nullptr;
  const int col = lane & 15;
  const int rb  = (lane >> 4) << 2;
  float* Cf = (float*)Cv + (long long)zb * sC;
  bf16*  Ch = (bf16*) Cv + (long long)zb * sC;

#pragma unroll
  for (int mi = 0; mi < 4; ++mi)
#pragma unroll
    for (int nj = 0; nj < 4; ++nj) {
      long long gn = tn + wc*64 + nj*16 + col;
      float bv_ = (EPI != 7 && bias && ks == 0) ? bias[gn] : 0.f;
#pragma unroll
      for (int r = 0; r < 4; ++r) {
        long long gm = tm + wr*64 + mi*16 + rb + r;
        float v = acc[mi][nj][r] + bv_;
        long long off = gm * (long long)ldc + gn;
        if (EPI == 0)      Cf[off] = v;
        else if (EPI == 3) { if (ksplit > 1) atomicAdd(&Cf[off], v); else Cf[off] += v; }
        else if (EPI == 5) wpair(Ch, off, pC, v);
        else if (EPI == 6) wpair(Ch, off, pC, v / (1.f + __expf(-v)));
        else {
          long long dlt = gm - gn;
          float dcy = (dlt >= 0) ? dtab[dlt] : 0.f;
          Ch[off] = __float2bfloat16(acc[mi][nj][r] * dcy);
        }
      }
    }
}

// ---------------------------------------------------------------------------
__global__ void zero_kernel(float4* __restrict__ p, long long n4) {
  long long i = (long long)blockIdx.x * blockDim.x + threadIdx.x;
  if (i < n4) p[i] = float4{0.f, 0.f, 0.f, 0.f};
}

__global__ void cast_kernel(const float* __restrict__ in,
                            bf16* __restrict__ out, long long n4) {
  long long i = (long long)blockIdx.x * blockDim.x + threadIdx.x;
  if (i >= n4) return;
  float4 v = ((const float4*)in)[i];
  bf16 a = __float2bfloat16(v.x), b = __float2bfloat16(v.y);
  bf16 c = __float2bfloat16(v.z), d = __float2bfloat16(v.w);
  ushort4 o{__builtin_bit_cast(unsigned short, a), __builtin_bit_cast(unsigned short, b),
            __builtin_bit_cast(unsigned short, c), __builtin_bit_cast(unsigned short, d)};
  ((ushort4*)out)[i] = o;
}

__global__ void cast_pair_kernel(const float* __restrict__ in,
                                 bf16* __restrict__ hi, bf16* __restrict__ lo,
                                 long long n) {
  long long i = (long long)blockIdx.x * blockDim.x + threadIdx.x;
  if (i >= n) return;
  float v = in[i];
  bf16 h = __float2bfloat16(v);
  hi[i] = h;
  lo[i] = __float2bfloat16(v - __bfloat162float(h));
}

__global__ void bias3_kernel(const float* __restrict__ q, const float* __restrict__ k,
                             const float* __restrict__ v, float* __restrict__ o) {
  int i = blockIdx.x * blockDim.x + threadIdx.x;
  if (i < DIM) o[i] = q[i];
  else if (i < 2*DIM) o[i] = k[i - DIM];
  else if (i < 3*DIM) o[i] = v[i - 2*DIM];
}

// decay table: dtab[h][n] = sigmoid(amp[h])^n, n in [0, SEQ]
__global__ void decay_kernel(const float* __restrict__ amp, float* __restrict__ dtab) {
  const int h = blockIdx.x, n = threadIdx.x;   // blockDim = SEQ+1? use 1025 via loop
  const float a = 1.f / (1.f + __expf(-amp[h]));
  for (int i = n; i <= SEQ; i += blockDim.x)
    dtab[h*(SEQ+1) + i] = powf(a, (float)i);
}

__global__ void ln_kernel(const float* __restrict__ in, bf16* __restrict__ out) {
  const int row = blockIdx.x;
  const int tid = threadIdx.x;          // 256
  const float4 v = ((const float4*)(in + (size_t)row*DIM))[tid];
  float s  = v.x + v.y + v.z + v.w;
  float s2 = v.x*v.x + v.y*v.y + v.z*v.z + v.w*v.w;
#pragma unroll
  for (int o = 32; o > 0; o >>= 1) { s += __shfl_xor(s, o); s2 += __shfl_xor(s2, o); }
  __shared__ float red[8];
  const int wv = tid >> 6;
  if ((tid & 63) == 0) { red[wv] = s; red[4 + wv] = s2; }
  __syncthreads();
  s  = red[0] + red[1] + red[2] + red[3];
  s2 = red[4] + red[5] + red[6] + red[7];
  const float mean = s * (1.f / DIM);
  const float var  = s2 * (1.f / DIM) - mean * mean;
  const float inv  = rsqrtf(var + 1e-5f);
  long long base = (long long)row*DIM + tid*4;
  wpair(out, base + 0, PQKV, (v.x - mean) * inv);
  wpair(out, base + 1, PQKV, (v.y - mean) * inv);
  wpair(out, base + 2, PQKV, (v.z - mean) * inv);
  wpair(out, base + 3, PQKV, (v.w - mean) * inv);
}

// qkv pair [B,L,3*DIM] -> qrot/krot pairs, qwb single [B,H,L,2*DQ]
__global__ void rotate_kernel(const bf16* __restrict__ qkv,
                              const float* __restrict__ pre, const float* __restrict__ pim,
                              const float* __restrict__ dtab,
                              bf16* __restrict__ qrot, bf16* __restrict__ krot,
                              bf16* __restrict__ qwb) {
  const int d = threadIdx.x, l = blockIdx.x, h = blockIdx.y, b = blockIdx.z;
  const float tr = pre[h*DQ + d], ti = pim[h*DQ + d];
  const float theta = atan2f(ti, tr);
  const long long rowb = (long long)(b*SEQ + l)*(3*DIM) + h*DQ + d;
  const float qv = __bfloat162float(qkv[rowb]) + __bfloat162float(qkv[rowb + PQKV3]);
  const float kv = __bfloat162float(qkv[rowb + DIM]) + __bfloat162float(qkv[rowb + DIM + PQKV3]);
  float sn, cs;
  sincosf(theta * (float)l, &sn, &cs);
  const long long dst = ((long long)(b*NH + h)*SEQ + l)*(2*DQ) + d;
  wpair(qrot, dst,      PROT, qv * cs);
  wpair(qrot, dst + DQ, PROT, qv * sn);
  wpair(krot, dst,      PROT, kv * cs);
  wpair(krot, dst + DQ, PROT, kv * sn);
  float sn2, cs2;
  sincosf(theta * (float)(l + 1), &sn2, &cs2);
  const float ad = dtab[h*(SEQ+1) + l + 1];
  qwb[dst]      = __float2bfloat16(qv * ad * cs2);
  qwb[dst + DQ] = __float2bfloat16(qv * ad * sn2);
}

// v (inside qkv pair) -> vt single [B,H,DQ,L]
__global__ void vt_kernel(const bf16* __restrict__ qkv, bf16* __restrict__ vt) {
  const int d = threadIdx.x, m = blockIdx.x, h = blockIdx.y, b = blockIdx.z;
  const long long src = (long long)(b*SEQ + m)*(3*DIM) + 2*DIM + h*DQ + d;
  const float v = __bfloat162float(qkv[src]) + __bfloat162float(qkv[src + PQKV3]);
  vt[((long long)(b*NH + h)*DQ + d)*SEQ + m] = __float2bfloat16(v);
}

// ret [B,H,L,DQ] f32 -> y pair [B,L,H*DQ] with silu
__global__ void siluret_kernel(const float* __restrict__ ret, bf16* __restrict__ y) {
  const int d = threadIdx.x, l = blockIdx.x, h = blockIdx.y, b = blockIdx.z;
  float r = ret[((long long)(b*NH + h)*SEQ + l)*DQ + d];
  float s = r / (1.f + __expf(-r));
  wpair(y, ((long long)(b*SEQ + l)*NH + h)*DQ + d, PY, s);
}

// lc_re/lc_im [H,DQ,DQ] -> lcc single [H, e, 2*DQ] = [lcr[d,e] ; -lci[d,e]]
__global__ void lccat_kernel(const float* __restrict__ lcr, const float* __restrict__ lci,
                             bf16* __restrict__ lc) {
  const int d = threadIdx.x, e = blockIdx.x, h = blockIdx.y;
  float vr = lcr[((long long)h*DQ + d)*DQ + e];
  float vi = lci[((long long)h*DQ + d)*DQ + e];
  long long dst = ((long long)h*DQ + e)*(2*DQ) + d;
  lc[dst]      = __float2bfloat16(vr);
  lc[dst + DQ] = __float2bfloat16(-vi);
}

// ---------------------------------------------------------------------------
extern "C" void kernel_launch(void* const* d_in, const int* in_sizes, int n_in,
                              void* d_out, int out_size, void* d_ws, size_t ws_size,
                              hipStream_t stream) {
  const float* x      = (const float*)d_in[0];
  const float* tin_w  = (const float*)d_in[1];
  const float* tin_b  = (const float*)d_in[2];
  const float* tout_w = (const float*)d_in[3];
  const float* tout_b = (const float*)d_in[4];
  const float* wq_w   = (const float*)d_in[5];
  const float* wq_b   = (const float*)d_in[6];
  const float* wk_w   = (const float*)d_in[7];
  const float* wk_b   = (const float*)d_in[8];
  const float* wv_w   = (const float*)d_in[9];
  const float* wv_b   = (const float*)d_in[10];
  const float* wo_w   = (const float*)d_in[11];
  const float* wo_b   = (const float*)d_in[12];
  const float* f1_w   = (const float*)d_in[13];
  const float* f1_b   = (const float*)d_in[14];
  const float* f2_w   = (const float*)d_in[15];
  const float* f2_b   = (const float*)d_in[16];
  const float* phz_re = (const float*)d_in[17];
  const float* phz_im = (const float*)d_in[18];
  const float* amp    = (const float*)d_in[19];
  const float* lc_re  = (const float*)d_in[20];
  const float* lc_im  = (const float*)d_in[21];
  (void)in_sizes; (void)n_in; (void)out_size; (void)ws_size;

  char* w = (char*)d_ws;
  auto alloc = [&](size_t bytes) {
    char* p = w; w += (bytes + 255) & ~(size_t)255; return p;
  };
  auto palloc = [&](long long elems) {       // hi/lo pair, lo at +elems
    return (bf16*)alloc((size_t)elems * 2 * 2);
  };

  const long long WP = 3LL*DIM*DIM;          // fused qkv weight plane
  float* h     = (float*)alloc((size_t)ROWS*DIM*4);
  float* ret   = (float*)alloc((size_t)BATCH*NH*SEQ*DQ*4);
  float* qkvbi = (float*)alloc((size_t)3*DIM*4);
  float* dtab  = (float*)alloc((size_t)NH*(SEQ+1)*4);
  bf16*  hb    = palloc(PQKV);
  bf16*  Wqkv  = palloc(WP);
  bf16*  Wol   = palloc((long long)DIM*DIM);
  bf16*  Wf1l  = palloc((long long)DH*DIM);
  bf16*  Wf2l  = palloc((long long)DIM*DH);
  bf16*  qkvb  = palloc(PQKV3);
  bf16*  lcc   = (bf16*)alloc((size_t)PLC*2);        // single plane
  bf16*  Wbig  = (bf16*)alloc((size_t)DIM*VOC*2);    // hi plane (tin + tout)
  bf16*  qrot  = palloc(PROT);
  bf16*  krot  = palloc(PROT);
  bf16*  qwb   = (bf16*)alloc((size_t)PROT*2);       // single plane
  bf16*  vtb   = (bf16*)alloc((size_t)PVT*2);        // single plane
  char*  s2    = w;                                  // Wbig_lo aliases here at end
  bf16*  Sb    = (bf16*)alloc((size_t)PS*2);         // single plane
  bf16*  mid   = palloc(PMID);
  // aliases (lifetimes disjoint):
  bf16*  xb      = (bf16*)d_out;    // bf16 x in d_out; dead before tout writes
  bf16*  Wbig_lo = (bf16*)s2;       // tout_w lo plane; Sb/mid dead by then
  bf16*  yb      = qkvb;            // silu(ret) pair; qkvb dead after rotate/vt

  auto cast = [&](const float* in, bf16* out, long long n) {
    long long n4 = n / 4;
    cast_kernel<<<dim3((unsigned)((n4 + 255) / 256)), dim3(256), 0, stream>>>(in, out, n4);
  };
  auto cast_pair = [&](const float* in, bf16* hi, bf16* lo, long long n) {
    cast_pair_kernel<<<dim3((unsigned)((n + 255) / 256)), dim3(256), 0, stream>>>(in, hi, lo, n);
  };
  auto zero = [&](float* p, long long nfloats) {
    long long n4 = nfloats / 4;
    zero_kernel<<<dim3((unsigned)((n4 + 255) / 256)), dim3(256), 0, stream>>>((float4*)p, n4);
  };

  // grid: x = m-tiles (fastest -> B-panel reuse in L2), y = n-tiles, z = batch*ksplit
  auto gemm = [&](int epi, int split, const bf16* A, long long sA, long long pA, int lda,
                  const bf16* B, long long sB, long long pB, int ldb, int bmod,
                  void* C, long long sC, long long pC, int ldc,
                  const float* bias, int hmod, int M, int N, int K, int batch, int ksplit) {
    dim3 g(M / BM, N / BN, batch * ksplit), blk(256);
    if (!split) {
      if (epi == 0) gemm_bt<0,0,0><<<g, blk, 0, stream>>>(A,sA,pA,lda,B,sB,pB,ldb,bmod,C,sC,pC,ldc,bias,hmod,M,N,K,ksplit);
      else          gemm_bt<3,0,0><<<g, blk, 0, stream>>>(A,sA,pA,lda,B,sB,pB,ldb,bmod,C,sC,pC,ldc,bias,hmod,M,N,K,ksplit);
    }
    else if (epi == 0) gemm_bt<0,1,1><<<g, blk, 0, stream>>>(A,sA,pA,lda,B,sB,pB,ldb,bmod,C,sC,pC,ldc,bias,hmod,M,N,K,ksplit);
    else if (epi == 3) gemm_bt<3,1,1><<<g, blk, 0, stream>>>(A,sA,pA,lda,B,sB,pB,ldb,bmod,C,sC,pC,ldc,bias,hmod,M,N,K,ksplit);
    else if (epi == 5) gemm_bt<5,1,1><<<g, blk, 0, stream>>>(A,sA,pA,lda,B,sB,pB,ldb,bmod,C,sC,pC,ldc,bias,hmod,M,N,K,ksplit);
    else if (epi == 6) gemm_bt<6,1,1><<<g, blk, 0, stream>>>(A,sA,pA,lda,B,sB,pB,ldb,bmod,C,sC,pC,ldc,bias,hmod,M,N,K,ksplit);
    else               gemm_bt<7,1,1><<<g, blk, 0, stream>>>(A,sA,pA,lda,B,sB,pB,ldb,bmod,C,sC,pC,ldc,bias,hmod,M,N,K,ksplit);
  };
  const int BIG = 1 << 30;

  // ---- input projection: h = x @ tin_w^T + tin_b  (split-K x10, atomic) ----
  cast(x, xb, (long long)ROWS*VOC);
  cast(tin_w, Wbig, (long long)DIM*VOC);
  zero(h, (long long)ROWS*DIM);
  gemm(3, 0, xb, 0, 0, VOC, Wbig, 0, 0, VOC, BIG, h, 0, 0, DIM, tin_b, 1,
       ROWS, DIM, VOC, 1, 10);

  for (int i = 0; i < DEPTH; ++i) {
    cast_pair(wq_w + (size_t)i*DIM*DIM, Wqkv,             Wqkv + WP,             (long long)DIM*DIM);
    cast_pair(wk_w + (size_t)i*DIM*DIM, Wqkv +   DIM*DIM, Wqkv + WP +   DIM*DIM, (long long)DIM*DIM);
    cast_pair(wv_w + (size_t)i*DIM*DIM, Wqkv + 2*DIM*DIM, Wqkv + WP + 2*DIM*DIM, (long long)DIM*DIM);
    cast_pair(wo_w + (size_t)i*DIM*DIM, Wol,  Wol  + (long long)DIM*DIM, (long long)DIM*DIM);
    cast_pair(f1_w + (size_t)i*DH*DIM,  Wf1l, Wf1l + (long long)DH*DIM,  (long long)DH*DIM);
    cast_pair(f2_w + (size_t)i*DIM*DH,  Wf2l, Wf2l + (long long)DIM*DH,  (long long)DIM*DH);
    bias3_kernel<<<dim3(12), dim3(256), 0, stream>>>(
        wq_b + i*DIM, wk_b + i*DIM, wv_b + i*DIM, qkvbi);
    decay_kernel<<<dim3(NH), dim3(256), 0, stream>>>(amp + i*NH, dtab);

    // retention
    ln_kernel<<<ROWS, 256, 0, stream>>>(h, hb);
    // fused qkv = hb @ [Wq;Wk;Wv]^T + [bq;bk;bv]
    gemm(5, 1, hb, 0, PQKV, DIM, Wqkv, 0, WP, DIM, BIG,
         qkvb, 0, PQKV3, 3*DIM, qkvbi, 1, ROWS, 3*DIM, DIM, 1, 1);
    rotate_kernel<<<dim3(SEQ, NH, BATCH), DQ, 0, stream>>>(
        qkvb, phz_re + i*NH*DQ, phz_im + i*NH*DQ, dtab, qrot, krot, qwb);
    vt_kernel<<<dim3(SEQ, NH, BATCH), DQ, 0, stream>>>(qkvb, vtb);
    lccat_kernel<<<dim3(DQ, NH), DQ, 0, stream>>>(
        lc_re + (size_t)i*NH*DQ*DQ, lc_im + (size_t)i*NH*DQ*DQ, lcc);
    // S = (Qrot Krot^T) * decay-mask  (3-pass, single-plane output)
    gemm(7, 1, qrot, (long long)SEQ*2*DQ, PROT, 2*DQ,
         krot, (long long)SEQ*2*DQ, PROT, 2*DQ, BIG,
         Sb, (long long)SEQ*SEQ, 0, SEQ, dtab, NH, SEQ, SEQ, 2*DQ, BATCH*NH, 1);
    // ret = S @ V (1-pass, split-K x4, atomic into zeroed ret) + cross (1-pass x2)
    zero(ret, (long long)BATCH*NH*SEQ*DQ);
    gemm(3, 0, Sb, (long long)SEQ*SEQ, 0, SEQ,
         vtb, (long long)DQ*SEQ, 0, SEQ, BIG,
         ret, (long long)SEQ*DQ, 0, DQ, nullptr, 1, SEQ, DQ, SEQ, BATCH*NH, 4);
    gemm(3, 0, qwb, (long long)SEQ*2*DQ, 0, 2*DQ,
         lcc, (long long)DQ*2*DQ, 0, 2*DQ, NH,
         ret, (long long)SEQ*DQ, 0, DQ, nullptr, 1, SEQ, DQ, 2*DQ, BATCH*NH, 2);
    siluret_kernel<<<dim3(SEQ, NH, BATCH), DQ, 0, stream>>>(ret, yb);
    // h += y @ wo^T + wo_b   (split-K x2)
    gemm(3, 1, yb, 0, PY, DIM, Wol, 0, (long long)DIM*DIM, DIM, BIG,
         h, 0, 0, DIM, wo_b + i*DIM, 1, ROWS, DIM, DIM, 1, 2);

    // FFN
    ln_kernel<<<ROWS, 256, 0, stream>>>(h, hb);
    gemm(6, 1, hb, 0, PQKV, DIM, Wf1l, 0, (long long)DH*DIM, DIM, BIG,
         mid, 0, PMID, DH, f1_b + i*DH, 1, ROWS, DH, DIM, 1, 1);
    gemm(3, 1, mid, 0, PMID, DH, Wf2l, 0, (long long)DIM*DH, DH, BIG,
         h, 0, 0, DIM, f2_b + i*DIM, 1, ROWS, DIM, DH, 1, 4);
  }

  // ---- output projection (split both operands; Sb/mid dead -> Wbig_lo alias) ----
  cast_pair(h, hb, hb + PQKV, PQKV);
  cast_pair(tout_w, Wbig, Wbig_lo, (long long)VOC*DIM);
  gemm(0, 1, hb, 0, PQKV, DIM, Wbig, 0, (long long)(Wbig_lo - Wbig), DIM, BIG,
       (float*)d_out, 0, 0, VOC, tout_b, 1, ROWS, VOC, DIM, 1, 1);
}

// Round 5
// 1954.688 us; speedup vs baseline: 1.8884x; 1.2064x over previous
//
#include <hip/hip_runtime.h>
#include <hip/hip_bf16.h>
#include <stdint.h>

#define DEPTH 4
#define DIM   1024
#define DH    4096
#define NH    8
#define DQ    128
#define VOC   32000
#define BATCH 2
#define SEQ   1024
#define ROWS  (BATCH*SEQ)   // 2048

#define PQKV  ((long long)ROWS*DIM)
#define PQKV3 ((long long)ROWS*3*DIM)
#define PROT  ((long long)BATCH*NH*SEQ*2*DQ)
#define PVT   ((long long)BATCH*NH*DQ*SEQ)
#define PS    ((long long)BATCH*NH*SEQ*SEQ)
#define PMID  ((long long)ROWS*DH)
#define PY    ((long long)ROWS*DIM)
#define PLC   ((long long)NH*DQ*2*DQ)

typedef __hip_bfloat16 bf16;
using f32x4  = __attribute__((ext_vector_type(4))) float;
using bf16x8 = __attribute__((ext_vector_type(8))) __bf16;

__device__ __forceinline__ void wpair(bf16* p, long long off, long long plane, float v) {
  bf16 hi = __float2bfloat16(v);
  p[off] = hi;
  p[off + plane] = __float2bfloat16(v - __bfloat162float(hi));
}

__device__ __forceinline__ void gload_lds16(const void* g, void* l) {
  __builtin_amdgcn_global_load_lds(
      (const __attribute__((address_space(1))) void*)g,
      (__attribute__((address_space(3))) void*)(uintptr_t)l,
      16, 0, 0);
}

// ---------------------------------------------------------------------------
// Batched GEMM: C[zb] = A[zb] (MxK rm) * B[zb%bmod]^T (NxK rm)
// Tile map: tm = blockIdx.x (m fastest -> consecutive blocks share B tile),
// tn = blockIdx.y. blockIdx.z = zb*ksplit + kslice (Kc = K/ksplit columns).
// SA/SB: operand has a bf16 lo plane at +pA/+pB; passes = Ah*Bh [+Al*Bh] [+Ah*Bl].
// EPI 0: f32 C = acc+bias              3: f32 C += acc+bias (atomic if ksplit>1)
//     5: pair C = acc+bias             6: pair C = silu(acc+bias)
//     7: bf16 C = acc*decay, decay = dtab[(zb%hmod)*(SEQ+1) + (row-col)] (row>=col)
// bias added by slice 0 only.
// ---------------------------------------------------------------------------
#define BM 128
#define BN 128
#define BKK 64
#define PL 16384   // one LDS plane: 128 rows x 64 bf16

template<int EPI, int SA, int SB>
__global__ __launch_bounds__(256, (SA || SB) ? 2 : 4)
void gemm_bt(const bf16* __restrict__ A, long long sA, long long pA, int lda,
             const bf16* __restrict__ B, long long sB, long long pB, int ldb, int bmod,
             void* __restrict__ Cv, long long sC, long long pC, int ldc,
             const float* __restrict__ bias, int hmod,
             int M, int N, int K, int ksplit)
{
  __shared__ int4 sbuf[1024 * (2 + SA + SB)];
  char* Asb = (char*)sbuf;
  char* Bsb = Asb + PL * (1 + SA);

  const int tid  = threadIdx.x;
  const int lane = tid & 63;
  const int wave = tid >> 6;
  const int wr   = wave >> 1;
  const int wc   = wave & 1;
  const int z    = blockIdx.z;
  const int zb   = z / ksplit;
  const int ks   = z - zb * ksplit;
  const int Kc   = K / ksplit;
  const int k0   = ks * Kc;
  const long long tm = (long long)blockIdx.x * BM;
  const long long tn = (long long)blockIdx.y * BN;

  const bf16* Ab = A + (long long)zb * sA;
  const bf16* Bb = B + (long long)(zb % bmod) * sB;

  f32x4 acc[4][4] = {};

  for (int kt = k0; kt < k0 + Kc; kt += BKK) {
#pragma unroll
    for (int j = 0; j < 4; ++j) {
      int slot0 = j*256 + wave*64;          // wave-uniform LDS base
      int i = slot0 + lane;
      int row = i >> 3;
      int gc  = (i & 7) ^ (row & 7);        // inverse-swizzled global chunk
      long long ga = (tm + row) * (long long)lda + kt + gc*8;
      long long gb = (tn + row) * (long long)ldb + kt + gc*8;
      gload_lds16(Ab + ga, Asb + slot0*16);
      if (SA) gload_lds16(Ab + pA + ga, Asb + PL + slot0*16);
      gload_lds16(Bb + gb, Bsb + slot0*16);
      if (SB) gload_lds16(Bb + pB + gb, Bsb + PL + slot0*16);
    }
    __syncthreads();
#pragma unroll
    for (int kh = 0; kh < 2; ++kh) {
      const int cb = kh*4 + (lane >> 4);
      int4 avh[4], bvh[4], avl[4], bvl[4];
#pragma unroll
      for (int mi = 0; mi < 4; ++mi) {
        int m = wr*64 + mi*16 + (lane & 15);
        int off = m*128 + ((cb ^ (m & 7)) << 4);
        avh[mi] = *(const int4*)(Asb + off);
        if (SA) avl[mi] = *(const int4*)(Asb + PL + off);
      }
#pragma unroll
      for (int nj = 0; nj < 4; ++nj) {
        int n = wc*64 + nj*16 + (lane & 15);
        int off = n*128 + ((cb ^ (n & 7)) << 4);
        bvh[nj] = *(const int4*)(Bsb + off);
        if (SB) bvl[nj] = *(const int4*)(Bsb + PL + off);
      }
#pragma unroll
      for (int mi = 0; mi < 4; ++mi)
#pragma unroll
        for (int nj = 0; nj < 4; ++nj)
          acc[mi][nj] = __builtin_amdgcn_mfma_f32_16x16x32_bf16(
              __builtin_bit_cast(bf16x8, avh[mi]),
              __builtin_bit_cast(bf16x8, bvh[nj]), acc[mi][nj], 0, 0, 0);
      if (SA)
#pragma unroll
        for (int mi = 0; mi < 4; ++mi)
#pragma unroll
          for (int nj = 0; nj < 4; ++nj)
            acc[mi][nj] = __builtin_amdgcn_mfma_f32_16x16x32_bf16(
                __builtin_bit_cast(bf16x8, avl[mi]),
                __builtin_bit_cast(bf16x8, bvh[nj]), acc[mi][nj], 0, 0, 0);
      if (SB)
#pragma unroll
        for (int mi = 0; mi < 4; ++mi)
#pragma unroll
          for (int nj = 0; nj < 4; ++nj)
            acc[mi][nj] = __builtin_amdgcn_mfma_f32_16x16x32_bf16(
                __builtin_bit_cast(bf16x8, avh[mi]),
                __builtin_bit_cast(bf16x8, bvl[nj]), acc[mi][nj], 0, 0, 0);
    }
    __syncthreads();
  }

  const float* dtab = (EPI == 7) ? bias + (zb % hmod) * (SEQ + 1) : nullptr;
  const int col = lane & 15;
  const int rb  = (lane >> 4) << 2;
  float* Cf = (float*)Cv + (long long)zb * sC;
  bf16*  Ch = (bf16*) Cv + (long long)zb * sC;

#pragma unroll
  for (int mi = 0; mi < 4; ++mi)
#pragma unroll
    for (int nj = 0; nj < 4; ++nj) {
      long long gn = tn + wc*64 + nj*16 + col;
      float bv_ = (EPI != 7 && bias && ks == 0) ? bias[gn] : 0.f;
#pragma unroll
      for (int r = 0; r < 4; ++r) {
        long long gm = tm + wr*64 + mi*16 + rb + r;
        float v = acc[mi][nj][r] + bv_;
        long long off = gm * (long long)ldc + gn;
        if (EPI == 0)      Cf[off] = v;
        else if (EPI == 3) { if (ksplit > 1) atomicAdd(&Cf[off], v); else Cf[off] += v; }
        else if (EPI == 5) wpair(Ch, off, pC, v);
        else if (EPI == 6) wpair(Ch, off, pC, v / (1.f + __expf(-v)));
        else {
          long long dlt = gm - gn;
          float dcy = (dlt >= 0) ? dtab[dlt] : 0.f;
          Ch[off] = __float2bfloat16(acc[mi][nj][r] * dcy);
        }
      }
    }
}

// ---------------------------------------------------------------------------
__global__ void zero_kernel(float4* __restrict__ p, long long n4) {
  long long i = (long long)blockIdx.x * blockDim.x + threadIdx.x;
  if (i < n4) p[i] = float4{0.f, 0.f, 0.f, 0.f};
}

__global__ void cast_kernel(const float* __restrict__ in,
                            bf16* __restrict__ out, long long n4) {
  long long i = (long long)blockIdx.x * blockDim.x + threadIdx.x;
  if (i >= n4) return;
  float4 v = ((const float4*)in)[i];
  bf16 a = __float2bfloat16(v.x), b = __float2bfloat16(v.y);
  bf16 c = __float2bfloat16(v.z), d = __float2bfloat16(v.w);
  ushort4 o{__builtin_bit_cast(unsigned short, a), __builtin_bit_cast(unsigned short, b),
            __builtin_bit_cast(unsigned short, c), __builtin_bit_cast(unsigned short, d)};
  ((ushort4*)out)[i] = o;
}

__global__ void cast_pair_kernel(const float* __restrict__ in,
                                 bf16* __restrict__ hi, bf16* __restrict__ lo,
                                 long long n) {
  long long i = (long long)blockIdx.x * blockDim.x + threadIdx.x;
  if (i >= n) return;
  float v = in[i];
  bf16 h = __float2bfloat16(v);
  hi[i] = h;
  lo[i] = __float2bfloat16(v - __bfloat162float(h));
}

__global__ void bias3_kernel(const float* __restrict__ q, const float* __restrict__ k,
                             const float* __restrict__ v, float* __restrict__ o) {
  int i = blockIdx.x * blockDim.x + threadIdx.x;
  if (i < DIM) o[i] = q[i];
  else if (i < 2*DIM) o[i] = k[i - DIM];
  else if (i < 3*DIM) o[i] = v[i - 2*DIM];
}

// decay table: dtab[h][n] = sigmoid(amp[h])^n, n in [0, SEQ]
__global__ void decay_kernel(const float* __restrict__ amp, float* __restrict__ dtab) {
  const int h = blockIdx.x, n = threadIdx.x;
  const float a = 1.f / (1.f + __expf(-amp[h]));
  for (int i = n; i <= SEQ; i += blockDim.x)
    dtab[h*(SEQ+1) + i] = powf(a, (float)i);
}

__global__ void ln_kernel(const float* __restrict__ in, bf16* __restrict__ out) {
  const int row = blockIdx.x;
  const int tid = threadIdx.x;          // 256
  const float4 v = ((const float4*)(in + (size_t)row*DIM))[tid];
  float s  = v.x + v.y + v.z + v.w;
  float s2 = v.x*v.x + v.y*v.y + v.z*v.z + v.w*v.w;
#pragma unroll
  for (int o = 32; o > 0; o >>= 1) { s += __shfl_xor(s, o); s2 += __shfl_xor(s2, o); }
  __shared__ float red[8];
  const int wv = tid >> 6;
  if ((tid & 63) == 0) { red[wv] = s; red[4 + wv] = s2; }
  __syncthreads();
  s  = red[0] + red[1] + red[2] + red[3];
  s2 = red[4] + red[5] + red[6] + red[7];
  const float mean = s * (1.f / DIM);
  const float var  = s2 * (1.f / DIM) - mean * mean;
  const float inv  = rsqrtf(var + 1e-5f);
  long long base = (long long)row*DIM + tid*4;
  wpair(out, base + 0, PQKV, (v.x - mean) * inv);
  wpair(out, base + 1, PQKV, (v.y - mean) * inv);
  wpair(out, base + 2, PQKV, (v.z - mean) * inv);
  wpair(out, base + 3, PQKV, (v.w - mean) * inv);
}

// qkv pair [B,L,3*DIM] -> qrot/krot/qwb single-plane [B,H,L,2*DQ]
__global__ void rotate_kernel(const bf16* __restrict__ qkv,
                              const float* __restrict__ pre, const float* __restrict__ pim,
                              const float* __restrict__ dtab,
                              bf16* __restrict__ qrot, bf16* __restrict__ krot,
                              bf16* __restrict__ qwb) {
  const int d = threadIdx.x, l = blockIdx.x, h = blockIdx.y, b = blockIdx.z;
  const float tr = pre[h*DQ + d], ti = pim[h*DQ + d];
  const float theta = atan2f(ti, tr);
  const long long rowb = (long long)(b*SEQ + l)*(3*DIM) + h*DQ + d;
  const float qv = __bfloat162float(qkv[rowb]) + __bfloat162float(qkv[rowb + PQKV3]);
  const float kv = __bfloat162float(qkv[rowb + DIM]) + __bfloat162float(qkv[rowb + DIM + PQKV3]);
  float sn, cs;
  sincosf(theta * (float)l, &sn, &cs);
  const long long dst = ((long long)(b*NH + h)*SEQ + l)*(2*DQ) + d;
  qrot[dst]      = __float2bfloat16(qv * cs);
  qrot[dst + DQ] = __float2bfloat16(qv * sn);
  krot[dst]      = __float2bfloat16(kv * cs);
  krot[dst + DQ] = __float2bfloat16(kv * sn);
  float sn2, cs2;
  sincosf(theta * (float)(l + 1), &sn2, &cs2);
  const float ad = dtab[h*(SEQ+1) + l + 1];
  qwb[dst]      = __float2bfloat16(qv * ad * cs2);
  qwb[dst + DQ] = __float2bfloat16(qv * ad * sn2);
}

// v (inside qkv pair) -> vt single [B,H,DQ,L], LDS-tiled transpose (coalesced)
__global__ void vt_kernel(const bf16* __restrict__ qkv, bf16* __restrict__ vt) {
  __shared__ float tile[64][65];
  const int t  = threadIdx.x;           // 256
  const int c  = t & 63, r4 = t >> 6;   // 4 rows/pass
  const int m0 = blockIdx.x * 64;       // L tile
  const int d0 = blockIdx.y * 64;       // DQ half
  const int h  = blockIdx.z & (NH - 1);
  const int b  = blockIdx.z >> 3;
#pragma unroll
  for (int rr = 0; rr < 64; rr += 4) {
    const int m = m0 + rr + r4;
    const long long src = (long long)(b*SEQ + m)*(3*DIM) + 2*DIM + h*DQ + d0 + c;
    tile[rr + r4][c] = __bfloat162float(qkv[src]) + __bfloat162float(qkv[src + PQKV3]);
  }
  __syncthreads();
#pragma unroll
  for (int rr = 0; rr < 64; rr += 4) {
    const int d = rr + r4;
    vt[((long long)(b*NH + h)*DQ + d0 + d)*SEQ + m0 + c] = __float2bfloat16(tile[c][d]);
  }
}

// ret [B,H,L,DQ] f32 -> y pair [B,L,H*DQ] with silu
__global__ void siluret_kernel(const float* __restrict__ ret, bf16* __restrict__ y) {
  const int d = threadIdx.x, l = blockIdx.x, h = blockIdx.y, b = blockIdx.z;
  float r = ret[((long long)(b*NH + h)*SEQ + l)*DQ + d];
  float s = r / (1.f + __expf(-r));
  wpair(y, ((long long)(b*SEQ + l)*NH + h)*DQ + d, PY, s);
}

// lc_re/lc_im [H,DQ,DQ] -> lcc single [H, e, 2*DQ] = [lcr[d,e] ; -lci[d,e]]
__global__ void lccat_kernel(const float* __restrict__ lcr, const float* __restrict__ lci,
                             bf16* __restrict__ lc) {
  const int d = threadIdx.x, e = blockIdx.x, h = blockIdx.y;
  float vr = lcr[((long long)h*DQ + d)*DQ + e];
  float vi = lci[((long long)h*DQ + d)*DQ + e];
  long long dst = ((long long)h*DQ + e)*(2*DQ) + d;
  lc[dst]      = __float2bfloat16(vr);
  lc[dst + DQ] = __float2bfloat16(-vi);
}

// ---------------------------------------------------------------------------
extern "C" void kernel_launch(void* const* d_in, const int* in_sizes, int n_in,
                              void* d_out, int out_size, void* d_ws, size_t ws_size,
                              hipStream_t stream) {
  const float* x      = (const float*)d_in[0];
  const float* tin_w  = (const float*)d_in[1];
  const float* tin_b  = (const float*)d_in[2];
  const float* tout_w = (const float*)d_in[3];
  const float* tout_b = (const float*)d_in[4];
  const float* wq_w   = (const float*)d_in[5];
  const float* wq_b   = (const float*)d_in[6];
  const float* wk_w   = (const float*)d_in[7];
  const float* wk_b   = (const float*)d_in[8];
  const float* wv_w   = (const float*)d_in[9];
  const float* wv_b   = (const float*)d_in[10];
  const float* wo_w   = (const float*)d_in[11];
  const float* wo_b   = (const float*)d_in[12];
  const float* f1_w   = (const float*)d_in[13];
  const float* f1_b   = (const float*)d_in[14];
  const float* f2_w   = (const float*)d_in[15];
  const float* f2_b   = (const float*)d_in[16];
  const float* phz_re = (const float*)d_in[17];
  const float* phz_im = (const float*)d_in[18];
  const float* amp    = (const float*)d_in[19];
  const float* lc_re  = (const float*)d_in[20];
  const float* lc_im  = (const float*)d_in[21];
  (void)in_sizes; (void)n_in; (void)out_size; (void)ws_size;

  char* w = (char*)d_ws;
  auto alloc = [&](size_t bytes) {
    char* p = w; w += (bytes + 255) & ~(size_t)255; return p;
  };
  auto palloc = [&](long long elems) {       // hi/lo pair, lo at +elems
    return (bf16*)alloc((size_t)elems * 2 * 2);
  };

  const long long WP = 3LL*DIM*DIM;          // fused qkv weight plane
  float* h     = (float*)alloc((size_t)ROWS*DIM*4);
  float* ret   = (float*)alloc((size_t)BATCH*NH*SEQ*DQ*4);
  float* qkvbi = (float*)alloc((size_t)3*DIM*4);
  float* dtab  = (float*)alloc((size_t)NH*(SEQ+1)*4);
  bf16*  hb    = palloc(PQKV);
  bf16*  Wqkv  = palloc(WP);
  bf16*  Wol   = palloc((long long)DIM*DIM);
  bf16*  Wf1l  = palloc((long long)DH*DIM);
  bf16*  Wf2l  = (bf16*)alloc((size_t)DIM*DH*2);     // hi only (2-pass f2)
  bf16*  qkvb  = palloc(PQKV3);
  bf16*  lcc   = (bf16*)alloc((size_t)PLC*2);        // single plane
  bf16*  Wbig  = (bf16*)alloc((size_t)DIM*VOC*2);    // hi only (tin + 2-pass tout)
  bf16*  qrot  = (bf16*)alloc((size_t)PROT*2);       // single plane
  bf16*  krot  = (bf16*)alloc((size_t)PROT*2);       // single plane
  bf16*  qwb   = (bf16*)alloc((size_t)PROT*2);       // single plane
  bf16*  vtb   = (bf16*)alloc((size_t)PVT*2);        // single plane
  bf16*  Sb    = (bf16*)alloc((size_t)PS*2);         // single plane
  bf16*  mid   = palloc(PMID);
  // aliases (lifetimes disjoint):
  bf16*  xb = (bf16*)d_out;    // bf16 x in d_out; dead before tout writes
  bf16*  yb = qkvb;            // silu(ret) pair; qkvb dead after rotate/vt

  auto cast = [&](const float* in, bf16* out, long long n) {
    long long n4 = n / 4;
    cast_kernel<<<dim3((unsigned)((n4 + 255) / 256)), dim3(256), 0, stream>>>(in, out, n4);
  };
  auto cast_pair = [&](const float* in, bf16* hi, bf16* lo, long long n) {
    cast_pair_kernel<<<dim3((unsigned)((n + 255) / 256)), dim3(256), 0, stream>>>(in, hi, lo, n);
  };
  auto zero = [&](float* p, long long nfloats) {
    long long n4 = nfloats / 4;
    zero_kernel<<<dim3((unsigned)((n4 + 255) / 256)), dim3(256), 0, stream>>>((float4*)p, n4);
  };

  // grid: x = m-tiles (fastest -> B-panel reuse in L2), y = n-tiles, z = batch*ksplit
  auto gemm = [&](int epi, int sa, int sb, const bf16* A, long long sA, long long pA, int lda,
                  const bf16* B, long long sB, long long pB, int ldb, int bmod,
                  void* C, long long sC, long long pC, int ldc,
                  const float* bias, int hmod, int M, int N, int K, int batch, int ksplit) {
    dim3 g(M / BM, N / BN, batch * ksplit), blk(256);
    if (epi == 3 && !sa && !sb)      gemm_bt<3,0,0><<<g, blk, 0, stream>>>(A,sA,pA,lda,B,sB,pB,ldb,bmod,C,sC,pC,ldc,bias,hmod,M,N,K,ksplit);
    else if (epi == 7)               gemm_bt<7,0,0><<<g, blk, 0, stream>>>(A,sA,pA,lda,B,sB,pB,ldb,bmod,C,sC,pC,ldc,bias,hmod,M,N,K,ksplit);
    else if (epi == 0 && sa && !sb)  gemm_bt<0,1,0><<<g, blk, 0, stream>>>(A,sA,pA,lda,B,sB,pB,ldb,bmod,C,sC,pC,ldc,bias,hmod,M,N,K,ksplit);
    else if (epi == 3 && sa && !sb)  gemm_bt<3,1,0><<<g, blk, 0, stream>>>(A,sA,pA,lda,B,sB,pB,ldb,bmod,C,sC,pC,ldc,bias,hmod,M,N,K,ksplit);
    else if (epi == 3)               gemm_bt<3,1,1><<<g, blk, 0, stream>>>(A,sA,pA,lda,B,sB,pB,ldb,bmod,C,sC,pC,ldc,bias,hmod,M,N,K,ksplit);
    else if (epi == 5)               gemm_bt<5,1,1><<<g, blk, 0, stream>>>(A,sA,pA,lda,B,sB,pB,ldb,bmod,C,sC,pC,ldc,bias,hmod,M,N,K,ksplit);
    else if (epi == 6)               gemm_bt<6,1,1><<<g, blk, 0, stream>>>(A,sA,pA,lda,B,sB,pB,ldb,bmod,C,sC,pC,ldc,bias,hmod,M,N,K,ksplit);
  };
  const int BIG = 1 << 30;

  // ---- input projection: h = x @ tin_w^T + tin_b  (split-K x10, atomic) ----
  cast(x, xb, (long long)ROWS*VOC);
  cast(tin_w, Wbig, (long long)DIM*VOC);
  zero(h, (long long)ROWS*DIM);
  gemm(3, 0, 0, xb, 0, 0, VOC, Wbig, 0, 0, VOC, BIG, h, 0, 0, DIM, tin_b, 1,
       ROWS, DIM, VOC, 1, 10);

  for (int i = 0; i < DEPTH; ++i) {
    cast_pair(wq_w + (size_t)i*DIM*DIM, Wqkv,             Wqkv + WP,             (long long)DIM*DIM);
    cast_pair(wk_w + (size_t)i*DIM*DIM, Wqkv +   DIM*DIM, Wqkv + WP +   DIM*DIM, (long long)DIM*DIM);
    cast_pair(wv_w + (size_t)i*DIM*DIM, Wqkv + 2*DIM*DIM, Wqkv + WP + 2*DIM*DIM, (long long)DIM*DIM);
    cast_pair(wo_w + (size_t)i*DIM*DIM, Wol,  Wol  + (long long)DIM*DIM, (long long)DIM*DIM);
    cast_pair(f1_w + (size_t)i*DH*DIM,  Wf1l, Wf1l + (long long)DH*DIM,  (long long)DH*DIM);
    cast(f2_w + (size_t)i*DIM*DH, Wf2l, (long long)DIM*DH);
    bias3_kernel<<<dim3(12), dim3(256), 0, stream>>>(
        wq_b + i*DIM, wk_b + i*DIM, wv_b + i*DIM, qkvbi);
    decay_kernel<<<dim3(NH), dim3(256), 0, stream>>>(amp + i*NH, dtab);

    // retention
    ln_kernel<<<ROWS, 256, 0, stream>>>(h, hb);
    // fused qkv = hb @ [Wq;Wk;Wv]^T + [bq;bk;bv]  (3-pass)
    gemm(5, 1, 1, hb, 0, PQKV, DIM, Wqkv, 0, WP, DIM, BIG,
         qkvb, 0, PQKV3, 3*DIM, qkvbi, 1, ROWS, 3*DIM, DIM, 1, 1);
    rotate_kernel<<<dim3(SEQ, NH, BATCH), DQ, 0, stream>>>(
        qkvb, phz_re + i*NH*DQ, phz_im + i*NH*DQ, dtab, qrot, krot, qwb);
    vt_kernel<<<dim3(SEQ/64, DQ/64, BATCH*NH), 256, 0, stream>>>(qkvb, vtb);
    lccat_kernel<<<dim3(DQ, NH), DQ, 0, stream>>>(
        lc_re + (size_t)i*NH*DQ*DQ, lc_im + (size_t)i*NH*DQ*DQ, lcc);
    // S = (Qrot Krot^T) * decay-mask   (1-pass)
    gemm(7, 0, 0, qrot, (long long)SEQ*2*DQ, 0, 2*DQ,
         krot, (long long)SEQ*2*DQ, 0, 2*DQ, BIG,
         Sb, (long long)SEQ*SEQ, 0, SEQ, dtab, NH, SEQ, SEQ, 2*DQ, BATCH*NH, 1);
    // ret = S @ V (1-pass, split-K x4, atomic) + cross (1-pass, split-K x2)
    zero(ret, (long long)BATCH*NH*SEQ*DQ);
    gemm(3, 0, 0, Sb, (long long)SEQ*SEQ, 0, SEQ,
         vtb, (long long)DQ*SEQ, 0, SEQ, BIG,
         ret, (long long)SEQ*DQ, 0, DQ, nullptr, 1, SEQ, DQ, SEQ, BATCH*NH, 4);
    gemm(3, 0, 0, qwb, (long long)SEQ*2*DQ, 0, 2*DQ,
         lcc, (long long)DQ*2*DQ, 0, 2*DQ, NH,
         ret, (long long)SEQ*DQ, 0, DQ, nullptr, 1, SEQ, DQ, 2*DQ, BATCH*NH, 2);
    siluret_kernel<<<dim3(SEQ, NH, BATCH), DQ, 0, stream>>>(ret, yb);
    // h += y @ wo^T + wo_b   (3-pass, split-K x2)
    gemm(3, 1, 1, yb, 0, PY, DIM, Wol, 0, (long long)DIM*DIM, DIM, BIG,
         h, 0, 0, DIM, wo_b + i*DIM, 1, ROWS, DIM, DIM, 1, 2);

    // FFN
    ln_kernel<<<ROWS, 256, 0, stream>>>(h, hb);
    gemm(6, 1, 1, hb, 0, PQKV, DIM, Wf1l, 0, (long long)DH*DIM, DIM, BIG,
         mid, 0, PMID, DH, f1_b + i*DH, 1, ROWS, DH, DIM, 1, 1);
    // f2: 2-pass (A=mid pair, B=Wf2 hi only), split-K x4
    gemm(3, 1, 0, mid, 0, PMID, DH, Wf2l, 0, 0, DH, BIG,
         h, 0, 0, DIM, f2_b + i*DIM, 1, ROWS, DIM, DH, 1, 4);
  }

  // ---- output projection: 2-pass (A=hb pair, B=tout_w hi only) ----
  cast_pair(h, hb, hb + PQKV, PQKV);
  cast(tout_w, Wbig, (long long)VOC*DIM);
  gemm(0, 1, 0, hb, 0, PQKV, DIM, Wbig, 0, 0, DIM, BIG,
       (float*)d_out, 0, 0, VOC, tout_b, 1, ROWS, VOC, DIM, 1, 1);
}

// Round 6
// 1864.156 us; speedup vs baseline: 1.9802x; 1.0486x over previous
//
#include <hip/hip_runtime.h>
#include <hip/hip_bf16.h>
#include <stdint.h>

#define DEPTH 4
#define DIM   1024
#define DH    4096
#define NH    8
#define DQ    128
#define VOC   32000
#define BATCH 2
#define SEQ   1024
#define ROWS  (BATCH*SEQ)   // 2048

#define PQKV  ((long long)ROWS*DIM)
#define PQKV3 ((long long)ROWS*3*DIM)
#define PROT  ((long long)BATCH*NH*SEQ*2*DQ)
#define PVT   ((long long)BATCH*NH*DQ*SEQ)
#define PS    ((long long)BATCH*NH*SEQ*SEQ)
#define PMID  ((long long)ROWS*DH)
#define PY    ((long long)ROWS*DIM)

typedef __hip_bfloat16 bf16;
using f32x4  = __attribute__((ext_vector_type(4))) float;
using bf16x8 = __attribute__((ext_vector_type(8))) __bf16;

__device__ __forceinline__ void wpair(bf16* p, long long off, long long plane, float v) {
  bf16 hi = __float2bfloat16(v);
  p[off] = hi;
  p[off + plane] = __float2bfloat16(v - __bfloat162float(hi));
}

__device__ __forceinline__ void gload_lds16(const void* g, void* l) {
  __builtin_amdgcn_global_load_lds(
      (const __attribute__((address_space(1))) void*)g,
      (__attribute__((address_space(3))) void*)(uintptr_t)l,
      16, 0, 0);
}

// ---------------------------------------------------------------------------
// Batched GEMM: C[zb] = A[zb] (MxK rm) * B[zb%bmod]^T (NxK rm)
// Tile map: tm = blockIdx.x (m fastest -> consecutive blocks share B tile),
// tn = blockIdx.y. blockIdx.z = zb*ksplit + kslice (Kc = K/ksplit columns).
// SA/SB: operand has a bf16 lo plane at +pA/+pB; passes = Ah*Bh [+Al*Bh] [+Ah*Bl].
// EPI 0: f32 C = acc+bias              3: f32 C += acc+bias (atomic if ksplit>1)
//     5: pair C = acc+bias             6: pair C = silu(acc+bias)
//     7: bf16 C = acc*decay, decay = dtab[(zb%hmod)*(SEQ+1) + (row-col)] (row>=col)
// causal: 1 = skip blocks fully above diagonal (S; skipped tiles never written)
//         2 = clamp K-loop to kend = tm+BM (PV reading causal S; skip if empty)
// bias added by slice 0 only.
// ---------------------------------------------------------------------------
#define BM 128
#define BN 128
#define BKK 64
#define PL 16384   // one LDS plane: 128 rows x 64 bf16

template<int EPI, int SA, int SB>
__global__ __launch_bounds__(256, (SA || SB) ? 2 : 4)
void gemm_bt(const bf16* __restrict__ A, long long sA, long long pA, int lda,
             const bf16* __restrict__ B, long long sB, long long pB, int ldb, int bmod,
             void* __restrict__ Cv, long long sC, long long pC, int ldc,
             const float* __restrict__ bias, int hmod,
             int M, int N, int K, int ksplit, int causal)
{
  __shared__ int4 sbuf[1024 * (2 + SA + SB)];
  char* Asb = (char*)sbuf;
  char* Bsb = Asb + PL * (1 + SA);

  const int tid  = threadIdx.x;
  const int lane = tid & 63;
  const int wave = tid >> 6;
  const int wr   = wave >> 1;
  const int wc   = wave & 1;
  const int z    = blockIdx.z;
  const int zb   = z / ksplit;
  const int ks   = z - zb * ksplit;
  const int Kc   = K / ksplit;
  const int k0   = ks * Kc;
  const int tm   = blockIdx.x * BM;
  const int tn   = blockIdx.y * BN;

  if (causal == 1 && tn >= tm + BM) return;      // fully-masked S tile
  int kend = k0 + Kc;
  if (causal == 2) {                              // PV: only m < tm+BM is valid S
    kend = min(kend, tm + BM);
    if (kend <= k0) return;
  }

  const bf16* Ab = A + (long long)zb * sA;
  const bf16* Bb = B + (long long)(zb % bmod) * sB;

  f32x4 acc[4][4] = {};

  for (int kt = k0; kt < kend; kt += BKK) {
#pragma unroll
    for (int j = 0; j < 4; ++j) {
      int slot0 = j*256 + wave*64;          // wave-uniform LDS base
      int i = slot0 + lane;
      int row = i >> 3;
      int gc  = (i & 7) ^ (row & 7);        // inverse-swizzled global chunk
      long long ga = (long long)(tm + row) * lda + kt + gc*8;
      long long gb = (long long)(tn + row) * ldb + kt + gc*8;
      gload_lds16(Ab + ga, Asb + slot0*16);
      if (SA) gload_lds16(Ab + pA + ga, Asb + PL + slot0*16);
      gload_lds16(Bb + gb, Bsb + slot0*16);
      if (SB) gload_lds16(Bb + pB + gb, Bsb + PL + slot0*16);
    }
    __syncthreads();
#pragma unroll
    for (int kh = 0; kh < 2; ++kh) {
      const int cb = kh*4 + (lane >> 4);
      int4 avh[4], bvh[4], avl[4], bvl[4];
#pragma unroll
      for (int mi = 0; mi < 4; ++mi) {
        int m = wr*64 + mi*16 + (lane & 15);
        int off = m*128 + ((cb ^ (m & 7)) << 4);
        avh[mi] = *(const int4*)(Asb + off);
        if (SA) avl[mi] = *(const int4*)(Asb + PL + off);
      }
#pragma unroll
      for (int nj = 0; nj < 4; ++nj) {
        int n = wc*64 + nj*16 + (lane & 15);
        int off = n*128 + ((cb ^ (n & 7)) << 4);
        bvh[nj] = *(const int4*)(Bsb + off);
        if (SB) bvl[nj] = *(const int4*)(Bsb + PL + off);
      }
#pragma unroll
      for (int mi = 0; mi < 4; ++mi)
#pragma unroll
        for (int nj = 0; nj < 4; ++nj)
          acc[mi][nj] = __builtin_amdgcn_mfma_f32_16x16x32_bf16(
              __builtin_bit_cast(bf16x8, avh[mi]),
              __builtin_bit_cast(bf16x8, bvh[nj]), acc[mi][nj], 0, 0, 0);
      if (SA)
#pragma unroll
        for (int mi = 0; mi < 4; ++mi)
#pragma unroll
          for (int nj = 0; nj < 4; ++nj)
            acc[mi][nj] = __builtin_amdgcn_mfma_f32_16x16x32_bf16(
                __builtin_bit_cast(bf16x8, avl[mi]),
                __builtin_bit_cast(bf16x8, bvh[nj]), acc[mi][nj], 0, 0, 0);
      if (SB)
#pragma unroll
        for (int mi = 0; mi < 4; ++mi)
#pragma unroll
          for (int nj = 0; nj < 4; ++nj)
            acc[mi][nj] = __builtin_amdgcn_mfma_f32_16x16x32_bf16(
                __builtin_bit_cast(bf16x8, avh[mi]),
                __builtin_bit_cast(bf16x8, bvl[nj]), acc[mi][nj], 0, 0, 0);
    }
    __syncthreads();
  }

  const float* dtab = (EPI == 7) ? bias + (zb % hmod) * (SEQ + 1) : nullptr;
  const int col = lane & 15;
  const int rb  = (lane >> 4) << 2;
  float* Cf = (float*)Cv + (long long)zb * sC;
  bf16*  Ch = (bf16*) Cv + (long long)zb * sC;

#pragma unroll
  for (int mi = 0; mi < 4; ++mi)
#pragma unroll
    for (int nj = 0; nj < 4; ++nj) {
      long long gn = tn + wc*64 + nj*16 + col;
      float bv_ = (EPI != 7 && bias && ks == 0) ? bias[gn] : 0.f;
#pragma unroll
      for (int r = 0; r < 4; ++r) {
        long long gm = tm + wr*64 + mi*16 + rb + r;
        float v = acc[mi][nj][r] + bv_;
        long long off = gm * (long long)ldc + gn;
        if (EPI == 0)      Cf[off] = v;
        else if (EPI == 3) { if (ksplit > 1) atomicAdd(&Cf[off], v); else Cf[off] += v; }
        else if (EPI == 5) wpair(Ch, off, pC, v);
        else if (EPI == 6) wpair(Ch, off, pC, v / (1.f + __expf(-v)));
        else {
          long long dlt = gm - gn;
          float dcy = (dlt >= 0) ? dtab[dlt] : 0.f;
          Ch[off] = __float2bfloat16(acc[mi][nj][r] * dcy);
        }
      }
    }
}

// ---------------------------------------------------------------------------
// Fused per-layer weight cast: Wqkv pair (3M), Wol pair (1M), Wf1 pair (4M),
// Wf2 single (4M) -> 12M flat elements, one launch.
__global__ void castw_kernel(const float* __restrict__ wq, const float* __restrict__ wk,
                             const float* __restrict__ wv, const float* __restrict__ wo,
                             const float* __restrict__ f1, const float* __restrict__ f2,
                             bf16* __restrict__ Wqkv, bf16* __restrict__ Wol,
                             bf16* __restrict__ Wf1, bf16* __restrict__ Wf2) {
  const long long S1 = (long long)DIM*DIM;        // 1M
  const long long WP = 3*S1;
  long long i = (long long)blockIdx.x * blockDim.x + threadIdx.x;
  if (i < 3*S1) {
    const float* src = (i < S1) ? wq : (i < 2*S1) ? wk : wv;
    float v = src[i & (S1-1)];
    bf16 h = __float2bfloat16(v);
    Wqkv[i] = h;
    Wqkv[i + WP] = __float2bfloat16(v - __bfloat162float(h));
  } else if (i < 4*S1) {
    long long j = i - 3*S1;
    float v = wo[j];
    bf16 h = __float2bfloat16(v);
    Wol[j] = h;
    Wol[j + S1] = __float2bfloat16(v - __bfloat162float(h));
  } else if (i < 8*S1) {
    long long j = i - 4*S1;
    float v = f1[j];
    bf16 h = __float2bfloat16(v);
    Wf1[j] = h;
    Wf1[j + 4*S1] = __float2bfloat16(v - __bfloat162float(h));
  } else if (i < 12*S1) {
    long long j = i - 8*S1;
    Wf2[j] = __float2bfloat16(f2[j]);
  }
}

// Fused per-layer misc prep: lccat (131072) + bias3 (3072) + decay (8*1025)
// + zero ret (524288 float4) in one launch.
#define MISC_LC   (NH*DQ*DQ)                 // 131072
#define MISC_B3   (MISC_LC + 3*DIM)          // +3072
#define MISC_DC   (MISC_B3 + NH*(SEQ+1))     // +8200
#define MISC_ZR   (MISC_DC + (BATCH*NH*SEQ*DQ)/4)
__global__ void misc_kernel(const float* __restrict__ lcr, const float* __restrict__ lci,
                            bf16* __restrict__ lc,
                            const float* __restrict__ bq, const float* __restrict__ bk,
                            const float* __restrict__ bv, float* __restrict__ qkvbi,
                            const float* __restrict__ amp, float* __restrict__ dtab,
                            float4* __restrict__ retz) {
  long long i = (long long)blockIdx.x * blockDim.x + threadIdx.x;
  if (i < MISC_LC) {
    int d = i & 127, e = (i >> 7) & 127, h = i >> 14;
    float vr = lcr[((long long)h*DQ + d)*DQ + e];
    float vi = lci[((long long)h*DQ + d)*DQ + e];
    long long dst = ((long long)h*DQ + e)*(2*DQ) + d;
    lc[dst]      = __float2bfloat16(vr);
    lc[dst + DQ] = __float2bfloat16(-vi);
  } else if (i < MISC_B3) {
    int j = (int)(i - MISC_LC);
    qkvbi[j] = (j < DIM) ? bq[j] : (j < 2*DIM) ? bk[j - DIM] : bv[j - 2*DIM];
  } else if (i < MISC_DC) {
    int j = (int)(i - MISC_B3);
    int h = j / (SEQ+1), n = j % (SEQ+1);
    float a = 1.f / (1.f + __expf(-amp[h]));
    dtab[j] = powf(a, (float)n);
  } else if (i < MISC_ZR) {
    retz[i - MISC_DC] = float4{0.f, 0.f, 0.f, 0.f};
  }
}

// tin prep: cast x (4-wide), cast tin_w (4-wide), zero h (float4), one launch.
#define TIN_X4 ((long long)ROWS*VOC/4)
#define TIN_W4 (TIN_X4 + (long long)DIM*VOC/4)
#define TIN_H4 (TIN_W4 + (long long)ROWS*DIM/4)
__global__ void tinprep_kernel(const float* __restrict__ x, bf16* __restrict__ xb,
                               const float* __restrict__ tw, bf16* __restrict__ twb,
                               float4* __restrict__ hz) {
  long long i = (long long)blockIdx.x * blockDim.x + threadIdx.x;
  const float* src; bf16* dst; long long j;
  if (i < TIN_X4)      { src = x;  dst = xb;  j = i; }
  else if (i < TIN_W4) { src = tw; dst = twb; j = i - TIN_X4; }
  else if (i < TIN_H4) { hz[i - TIN_W4] = float4{0.f,0.f,0.f,0.f}; return; }
  else return;
  float4 v = ((const float4*)src)[j];
  ushort4 o{__builtin_bit_cast(unsigned short, __float2bfloat16(v.x)),
            __builtin_bit_cast(unsigned short, __float2bfloat16(v.y)),
            __builtin_bit_cast(unsigned short, __float2bfloat16(v.z)),
            __builtin_bit_cast(unsigned short, __float2bfloat16(v.w))};
  ((ushort4*)dst)[j] = o;
}

// tail prep: pair-cast h -> hb (scalar) + cast tout_w (4-wide), one launch.
#define TAIL_H (PQKV)
#define TAIL_W (TAIL_H + (long long)VOC*DIM/4)
__global__ void tailprep_kernel(const float* __restrict__ h, bf16* __restrict__ hb,
                                const float* __restrict__ tw, bf16* __restrict__ twb) {
  long long i = (long long)blockIdx.x * blockDim.x + threadIdx.x;
  if (i < TAIL_H) {
    float v = h[i];
    bf16 hi = __float2bfloat16(v);
    hb[i] = hi;
    hb[i + PQKV] = __float2bfloat16(v - __bfloat162float(hi));
  } else if (i < TAIL_W) {
    long long j = i - TAIL_H;
    float4 v = ((const float4*)tw)[j];
    ushort4 o{__builtin_bit_cast(unsigned short, __float2bfloat16(v.x)),
              __builtin_bit_cast(unsigned short, __float2bfloat16(v.y)),
              __builtin_bit_cast(unsigned short, __float2bfloat16(v.z)),
              __builtin_bit_cast(unsigned short, __float2bfloat16(v.w))};
    ((ushort4*)twb)[j] = o;
  }
}

__global__ void ln_kernel(const float* __restrict__ in, bf16* __restrict__ out) {
  const int row = blockIdx.x;
  const int tid = threadIdx.x;          // 256
  const float4 v = ((const float4*)(in + (size_t)row*DIM))[tid];
  float s  = v.x + v.y + v.z + v.w;
  float s2 = v.x*v.x + v.y*v.y + v.z*v.z + v.w*v.w;
#pragma unroll
  for (int o = 32; o > 0; o >>= 1) { s += __shfl_xor(s, o); s2 += __shfl_xor(s2, o); }
  __shared__ float red[8];
  const int wv = tid >> 6;
  if ((tid & 63) == 0) { red[wv] = s; red[4 + wv] = s2; }
  __syncthreads();
  s  = red[0] + red[1] + red[2] + red[3];
  s2 = red[4] + red[5] + red[6] + red[7];
  const float mean = s * (1.f / DIM);
  const float var  = s2 * (1.f / DIM) - mean * mean;
  const float inv  = rsqrtf(var + 1e-5f);
  long long base = (long long)row*DIM + tid*4;
  wpair(out, base + 0, PQKV, (v.x - mean) * inv);
  wpair(out, base + 1, PQKV, (v.y - mean) * inv);
  wpair(out, base + 2, PQKV, (v.z - mean) * inv);
  wpair(out, base + 3, PQKV, (v.w - mean) * inv);
}

// qkv pair [B,L,3*DIM] -> qrot/krot/qwb single-plane [B,H,L,2*DQ]
__global__ void rotate_kernel(const bf16* __restrict__ qkv,
                              const float* __restrict__ pre, const float* __restrict__ pim,
                              const float* __restrict__ dtab,
                              bf16* __restrict__ qrot, bf16* __restrict__ krot,
                              bf16* __restrict__ qwb) {
  const int d = threadIdx.x, l = blockIdx.x, h = blockIdx.y, b = blockIdx.z;
  const float tr = pre[h*DQ + d], ti = pim[h*DQ + d];
  const float theta = atan2f(ti, tr);
  const long long rowb = (long long)(b*SEQ + l)*(3*DIM) + h*DQ + d;
  const float qv = __bfloat162float(qkv[rowb]) + __bfloat162float(qkv[rowb + PQKV3]);
  const float kv = __bfloat162float(qkv[rowb + DIM]) + __bfloat162float(qkv[rowb + DIM + PQKV3]);
  float sn, cs;
  sincosf(theta * (float)l, &sn, &cs);
  const long long dst = ((long long)(b*NH + h)*SEQ + l)*(2*DQ) + d;
  qrot[dst]      = __float2bfloat16(qv * cs);
  qrot[dst + DQ] = __float2bfloat16(qv * sn);
  krot[dst]      = __float2bfloat16(kv * cs);
  krot[dst + DQ] = __float2bfloat16(kv * sn);
  float sn2, cs2;
  sincosf(theta * (float)(l + 1), &sn2, &cs2);
  const float ad = dtab[h*(SEQ+1) + l + 1];
  qwb[dst]      = __float2bfloat16(qv * ad * cs2);
  qwb[dst + DQ] = __float2bfloat16(qv * ad * sn2);
}

// v (inside qkv pair) -> vt single [B,H,DQ,L], LDS-tiled transpose (coalesced)
__global__ void vt_kernel(const bf16* __restrict__ qkv, bf16* __restrict__ vt) {
  __shared__ float tile[64][65];
  const int t  = threadIdx.x;           // 256
  const int c  = t & 63, r4 = t >> 6;   // 4 rows/pass
  const int m0 = blockIdx.x * 64;       // L tile
  const int d0 = blockIdx.y * 64;       // DQ half
  const int h  = blockIdx.z & (NH - 1);
  const int b  = blockIdx.z >> 3;
#pragma unroll
  for (int rr = 0; rr < 64; rr += 4) {
    const int m = m0 + rr + r4;
    const long long src = (long long)(b*SEQ + m)*(3*DIM) + 2*DIM + h*DQ + d0 + c;
    tile[rr + r4][c] = __bfloat162float(qkv[src]) + __bfloat162float(qkv[src + PQKV3]);
  }
  __syncthreads();
#pragma unroll
  for (int rr = 0; rr < 64; rr += 4) {
    const int d = rr + r4;
    vt[((long long)(b*NH + h)*DQ + d0 + d)*SEQ + m0 + c] = __float2bfloat16(tile[c][d]);
  }
}

// ret [B,H,L,DQ] f32 -> y pair [B,L,H*DQ] with silu
__global__ void siluret_kernel(const float* __restrict__ ret, bf16* __restrict__ y) {
  const int d = threadIdx.x, l = blockIdx.x, h = blockIdx.y, b = blockIdx.z;
  float r = ret[((long long)(b*NH + h)*SEQ + l)*DQ + d];
  float s = r / (1.f + __expf(-r));
  wpair(y, ((long long)(b*SEQ + l)*NH + h)*DQ + d, PY, s);
}

// ---------------------------------------------------------------------------
extern "C" void kernel_launch(void* const* d_in, const int* in_sizes, int n_in,
                              void* d_out, int out_size, void* d_ws, size_t ws_size,
                              hipStream_t stream) {
  const float* x      = (const float*)d_in[0];
  const float* tin_w  = (const float*)d_in[1];
  const float* tin_b  = (const float*)d_in[2];
  const float* tout_w = (const float*)d_in[3];
  const float* tout_b = (const float*)d_in[4];
  const float* wq_w   = (const float*)d_in[5];
  const float* wq_b   = (const float*)d_in[6];
  const float* wk_w   = (const float*)d_in[7];
  const float* wk_b   = (const float*)d_in[8];
  const float* wv_w   = (const float*)d_in[9];
  const float* wv_b   = (const float*)d_in[10];
  const float* wo_w   = (const float*)d_in[11];
  const float* wo_b   = (const float*)d_in[12];
  const float* f1_w   = (const float*)d_in[13];
  const float* f1_b   = (const float*)d_in[14];
  const float* f2_w   = (const float*)d_in[15];
  const float* f2_b   = (const float*)d_in[16];
  const float* phz_re = (const float*)d_in[17];
  const float* phz_im = (const float*)d_in[18];
  const float* amp    = (const float*)d_in[19];
  const float* lc_re  = (const float*)d_in[20];
  const float* lc_im  = (const float*)d_in[21];
  (void)in_sizes; (void)n_in; (void)out_size; (void)ws_size;

  char* w = (char*)d_ws;
  auto alloc = [&](size_t bytes) {
    char* p = w; w += (bytes + 255) & ~(size_t)255; return p;
  };
  auto palloc = [&](long long elems) {       // hi/lo pair, lo at +elems
    return (bf16*)alloc((size_t)elems * 2 * 2);
  };

  const long long WP = 3LL*DIM*DIM;          // fused qkv weight plane
  float* h     = (float*)alloc((size_t)ROWS*DIM*4);
  float* ret   = (float*)alloc((size_t)BATCH*NH*SEQ*DQ*4);
  float* qkvbi = (float*)alloc((size_t)3*DIM*4);
  float* dtab  = (float*)alloc((size_t)NH*(SEQ+1)*4);
  bf16*  hb    = palloc(PQKV);
  bf16*  Wqkv  = palloc(WP);
  bf16*  Wol   = palloc((long long)DIM*DIM);
  bf16*  Wf1l  = palloc((long long)DH*DIM);
  bf16*  Wf2l  = (bf16*)alloc((size_t)DIM*DH*2);     // hi only (2-pass f2)
  bf16*  qkvb  = palloc(PQKV3);
  bf16*  lcc   = (bf16*)alloc((size_t)NH*DQ*2*DQ*2); // single plane
  bf16*  Wbig  = (bf16*)alloc((size_t)DIM*VOC*2);    // hi only (tin + 2-pass tout)
  bf16*  qrot  = (bf16*)alloc((size_t)PROT*2);       // single plane
  bf16*  krot  = (bf16*)alloc((size_t)PROT*2);       // single plane
  bf16*  qwb   = (bf16*)alloc((size_t)PROT*2);       // single plane
  bf16*  vtb   = (bf16*)alloc((size_t)PVT*2);        // single plane
  bf16*  Sb    = (bf16*)alloc((size_t)PS*2);         // single plane
  bf16*  mid   = palloc(PMID);
  // aliases (lifetimes disjoint):
  bf16*  xb = (bf16*)d_out;    // bf16 x in d_out; dead before tout writes
  bf16*  yb = qkvb;            // silu(ret) pair; qkvb dead after rotate/vt

  // grid: x = m-tiles (fastest -> B-panel reuse in L2), y = n-tiles, z = batch*ksplit
  auto gemm = [&](int epi, int sa, int sb, const bf16* A, long long sA, long long pA, int lda,
                  const bf16* B, long long sB, long long pB, int ldb, int bmod,
                  void* C, long long sC, long long pC, int ldc,
                  const float* bias, int hmod, int M, int N, int K, int batch,
                  int ksplit, int causal) {
    dim3 g(M / BM, N / BN, batch * ksplit), blk(256);
    if (epi == 3 && !sa && !sb)      gemm_bt<3,0,0><<<g, blk, 0, stream>>>(A,sA,pA,lda,B,sB,pB,ldb,bmod,C,sC,pC,ldc,bias,hmod,M,N,K,ksplit,causal);
    else if (epi == 7)               gemm_bt<7,0,0><<<g, blk, 0, stream>>>(A,sA,pA,lda,B,sB,pB,ldb,bmod,C,sC,pC,ldc,bias,hmod,M,N,K,ksplit,causal);
    else if (epi == 0 && sa && !sb)  gemm_bt<0,1,0><<<g, blk, 0, stream>>>(A,sA,pA,lda,B,sB,pB,ldb,bmod,C,sC,pC,ldc,bias,hmod,M,N,K,ksplit,causal);
    else if (epi == 3 && sa && !sb)  gemm_bt<3,1,0><<<g, blk, 0, stream>>>(A,sA,pA,lda,B,sB,pB,ldb,bmod,C,sC,pC,ldc,bias,hmod,M,N,K,ksplit,causal);
    else if (epi == 3)               gemm_bt<3,1,1><<<g, blk, 0, stream>>>(A,sA,pA,lda,B,sB,pB,ldb,bmod,C,sC,pC,ldc,bias,hmod,M,N,K,ksplit,causal);
    else if (epi == 5)               gemm_bt<5,1,1><<<g, blk, 0, stream>>>(A,sA,pA,lda,B,sB,pB,ldb,bmod,C,sC,pC,ldc,bias,hmod,M,N,K,ksplit,causal);
    else if (epi == 6)               gemm_bt<6,1,1><<<g, blk, 0, stream>>>(A,sA,pA,lda,B,sB,pB,ldb,bmod,C,sC,pC,ldc,bias,hmod,M,N,K,ksplit,causal);
  };
  const int BIG = 1 << 30;

  // ---- input projection: h = x @ tin_w^T + tin_b  (split-K x10, atomic) ----
  {
    long long tot = TIN_H4;
    tinprep_kernel<<<dim3((unsigned)((tot + 255) / 256)), dim3(256), 0, stream>>>(
        x, xb, tin_w, Wbig, (float4*)h);
  }
  gemm(3, 0, 0, xb, 0, 0, VOC, Wbig, 0, 0, VOC, BIG, h, 0, 0, DIM, tin_b, 1,
       ROWS, DIM, VOC, 1, 10, 0);

  for (int i = 0; i < DEPTH; ++i) {
    {
      long long tot = 12LL*DIM*DIM;
      castw_kernel<<<dim3((unsigned)((tot + 255) / 256)), dim3(256), 0, stream>>>(
          wq_w + (size_t)i*DIM*DIM, wk_w + (size_t)i*DIM*DIM, wv_w + (size_t)i*DIM*DIM,
          wo_w + (size_t)i*DIM*DIM, f1_w + (size_t)i*DH*DIM, f2_w + (size_t)i*DIM*DH,
          Wqkv, Wol, Wf1l, Wf2l);
      misc_kernel<<<dim3((unsigned)((MISC_ZR + 255) / 256)), dim3(256), 0, stream>>>(
          lc_re + (size_t)i*NH*DQ*DQ, lc_im + (size_t)i*NH*DQ*DQ, lcc,
          wq_b + i*DIM, wk_b + i*DIM, wv_b + i*DIM, qkvbi,
          amp + i*NH, dtab, (float4*)ret);
    }

    // retention
    ln_kernel<<<ROWS, 256, 0, stream>>>(h, hb);
    // fused qkv = hb @ [Wq;Wk;Wv]^T + [bq;bk;bv]  (3-pass)
    gemm(5, 1, 1, hb, 0, PQKV, DIM, Wqkv, 0, WP, DIM, BIG,
         qkvb, 0, PQKV3, 3*DIM, qkvbi, 1, ROWS, 3*DIM, DIM, 1, 1, 0);
    rotate_kernel<<<dim3(SEQ, NH, BATCH), DQ, 0, stream>>>(
        qkvb, phz_re + i*NH*DQ, phz_im + i*NH*DQ, dtab, qrot, krot, qwb);
    vt_kernel<<<dim3(SEQ/64, DQ/64, BATCH*NH), 256, 0, stream>>>(qkvb, vtb);
    // S = (Qrot Krot^T) * decay-mask   (1-pass, causal tile-skip)
    gemm(7, 0, 0, qrot, (long long)SEQ*2*DQ, 0, 2*DQ,
         krot, (long long)SEQ*2*DQ, 0, 2*DQ, BIG,
         Sb, (long long)SEQ*SEQ, 0, SEQ, dtab, NH, SEQ, SEQ, 2*DQ, BATCH*NH, 1, 1);
    // ret = S @ V (1-pass, split-K x4, atomic, causal K-clamp) + cross (x2)
    gemm(3, 0, 0, Sb, (long long)SEQ*SEQ, 0, SEQ,
         vtb, (long long)DQ*SEQ, 0, SEQ, BIG,
         ret, (long long)SEQ*DQ, 0, DQ, nullptr, 1, SEQ, DQ, SEQ, BATCH*NH, 4, 2);
    gemm(3, 0, 0, qwb, (long long)SEQ*2*DQ, 0, 2*DQ,
         lcc, (long long)DQ*2*DQ, 0, 2*DQ, NH,
         ret, (long long)SEQ*DQ, 0, DQ, nullptr, 1, SEQ, DQ, 2*DQ, BATCH*NH, 2, 0);
    siluret_kernel<<<dim3(SEQ, NH, BATCH), DQ, 0, stream>>>(ret, yb);
    // h += y @ wo^T + wo_b   (3-pass, split-K x2)
    gemm(3, 1, 1, yb, 0, PY, DIM, Wol, 0, (long long)DIM*DIM, DIM, BIG,
         h, 0, 0, DIM, wo_b + i*DIM, 1, ROWS, DIM, DIM, 1, 2, 0);

    // FFN
    ln_kernel<<<ROWS, 256, 0, stream>>>(h, hb);
    gemm(6, 1, 1, hb, 0, PQKV, DIM, Wf1l, 0, (long long)DH*DIM, DIM, BIG,
         mid, 0, PMID, DH, f1_b + i*DH, 1, ROWS, DH, DIM, 1, 1, 0);
    // f2: 2-pass (A=mid pair, B=Wf2 hi only), split-K x4
    gemm(3, 1, 0, mid, 0, PMID, DH, Wf2l, 0, 0, DH, BIG,
         h, 0, 0, DIM, f2_b + i*DIM, 1, ROWS, DIM, DH, 1, 4, 0);
  }

  // ---- output projection: 2-pass (A=hb pair, B=tout_w hi only) ----
  tailprep_kernel<<<dim3((unsigned)((TAIL_W + 255) / 256)), dim3(256), 0, stream>>>(
      h, hb, tout_w, Wbig);
  gemm(0, 1, 0, hb, 0, PQKV, DIM, Wbig, 0, 0, DIM, BIG,
       (float*)d_out, 0, 0, VOC, tout_b, 1, ROWS, VOC, DIM, 1, 1, 0);
}